// Round 6
// baseline (749.078 us; speedup 1.0000x reference)
//
#include <hip/hip_runtime.h>
#include <stdint.h>

// ---------------- types / helpers ----------------
typedef short bf16x8 __attribute__((ext_vector_type(8)));
typedef float f32x4 __attribute__((ext_vector_type(4)));

#define AS1 __attribute__((address_space(1)))
#define AS3 __attribute__((address_space(3)))

static __device__ __forceinline__ void gl16(const void* g, void* l) {
  __builtin_amdgcn_global_load_lds((const AS1 void*)g, (AS3 void*)l, 16, 0, 0);
}

static __device__ __forceinline__ unsigned short f2bf(float f) {
  unsigned u = __float_as_uint(f);
  u = u + 0x7fffu + ((u >> 16) & 1u);
  return (unsigned short)(u >> 16);
}
static __device__ __forceinline__ float bf2f(unsigned short h) {
  return __uint_as_float(((unsigned)h) << 16);
}
static __device__ __forceinline__ float mishf(float x) {
  float sp = fmaxf(x, 0.f) + log1pf(expf(-fabsf(x)));
  float e2 = expf(-2.f * sp);
  float th = (1.f - e2) / (1.f + e2);
  return x * th;
}

// geometry
#define NIMG 8
#define HH 128
#define WW 128
#define HP 130
#define CIN 256
#define MPIX (NIMG * HH * WW)       // 131072
#define KTOT 2304                   // 72 steps of 32
#define FGCNT (MPIX * 9)            // 1179648
#define TSCNT (MPIX * 9 * 4)        // 4718592

__device__ __constant__ float AW[9] = {456.f, 912.f, 1824.f, 320.f, 640.f, 1280.f, 224.f, 448.f, 896.f};
__device__ __constant__ float AH[9] = {224.f, 448.f, 896.f, 320.f, 640.f, 1280.f, 448.f, 896.f, 1792.f};

// ---------------- K0a: conv weights -> Wt2[s][oc][32] bf16, s = kh*24+kw*8+icb ----------------
__global__ __launch_bounds__(256) void k_wt(const float* __restrict__ Wb,
                                            unsigned short* __restrict__ Wt2) {
  int d = blockIdx.x * 256 + threadIdx.x;  // 589824 = 72*256*32
  int c = d & 31, oc = (d >> 5) & 255, s = d >> 13;
  int kh = s / 24, r = s % 24, kw = r >> 3, icb = r & 7;
  int ic = icb * 32 + c;
  Wt2[d] = f2bf(Wb[((oc * 256 + ic) * 3 + kh) * 3 + kw]);
}

// ---------------- K0b: x (NCHW f32) -> xt2 (channel-blocked padded) interior ----------------
// xt2 layout: [icb(8)*8+n][130][130][32] bf16
__global__ __launch_bounds__(256) void k_tr(const float* __restrict__ x,
                                            unsigned short* __restrict__ xt2) {
  __shared__ float tile[32][129];
  int b = blockIdx.x;  // 8 n * 128 h * 8 icb = 8192
  int icb = b & 7, h = (b >> 3) & 127, n = b >> 10;
  int t = threadIdx.x;
  const float* src = x + (((size_t)(n * 256 + icb * 32) * 128 + h) * 128);
#pragma unroll
  for (int i = 0; i < 4; ++i) {
    int idx = t + 256 * i;          // 1024 float4 units
    int w4 = idx & 31, ic = idx >> 5;
    float4 v = *(const float4*)(src + (size_t)ic * 16384 + w4 * 4);
    tile[ic][w4 * 4 + 0] = v.x; tile[ic][w4 * 4 + 1] = v.y;
    tile[ic][w4 * 4 + 2] = v.z; tile[ic][w4 * 4 + 3] = v.w;
  }
  __syncthreads();
#pragma unroll
  for (int i = 0; i < 8; ++i) {
    int idx = t + 256 * i;          // 2048 bf16-pairs
    int icp = idx & 15, w = idx >> 4;
    unsigned lo = f2bf(tile[icp * 2][w]);
    unsigned hi = f2bf(tile[icp * 2 + 1][w]);
    size_t pix = ((size_t)(icb * 8 + n) * HP + (h + 1)) * HP + (w + 1);
    *(unsigned*)(xt2 + pix * 32 + icp * 2) = lo | (hi << 16);
  }
}

// ---------------- K0c: zero padded borders of xt2 ----------------
__global__ __launch_bounds__(256) void k_bord(unsigned short* __restrict__ xt2) {
  int tid = blockIdx.x * 256 + threadIdx.x;  // 64 planes * 516 border pix * 4 chunks = 132096
  int chunk = tid & 3, pix = tid >> 2;
  int nn = pix / 516, bp = pix % 516;        // nn = icb*8+n plane
  int hp, wp;
  if (bp < 130) { hp = 0; wp = bp; }
  else if (bp < 260) { hp = 129; wp = bp - 130; }
  else { int r = bp - 260; hp = 1 + (r >> 1); wp = (r & 1) ? 129 : 0; }
  size_t off = (((size_t)nn * HP + hp) * HP + wp) * 32 + chunk * 8;
  uint4 z = {0u, 0u, 0u, 0u};
  *(uint4*)(xt2 + off) = z;
}

// ---------------- K1: conv3x3 implicit GEMM ----------------
// M=131072, N=256, K=2304 (72 steps of 32: s=(kh,kw,icb)). BM=128 x BN=256, 8 waves,
// wave tile 64x64, acc[4][4]=64 f32/thread (no spill: R2 lesson).
// LDS: SUBTILED per buffer  A:[q4][128pix][16B] (8KB)  B:[q4][256oc][16B] (16KB)
//   -> measured 0 bank conflicts (R2-R4). gl16 dest stays linear (wave region =
//   contiguous subtile slice); SOURCE is the inverse permutation (stride-64 lanes).
// Pipeline: 4 buffers, prefetch depth 3, counted vmcnt(6) (T4), ONE barrier/step.
//   Race: each wave drains its own stage-s (vmcnt) before s_barrier; barrier also
//   orders step s-1 frag-reads before overwrite of buf[(s+3)&3] == buf[(s-1)&3].
// Full unroll folds all s-derived addressing to base+constant (kills R5's VALU 49%).
__global__ __launch_bounds__(512) void k_conv(const unsigned short* __restrict__ xt2,
                                              const unsigned short* __restrict__ Wt2,
                                              const float* __restrict__ b_base,
                                              unsigned short* __restrict__ yt2,
                                              float* __restrict__ statsA) {
  __shared__ __align__(16) char lds[98304];    // 4 x 24KB
  int t = threadIdx.x;
  int lane = t & 63, w4 = t >> 6;              // 8 waves
  int wr = w4 >> 2, wc = w4 & 3;               // 2M x 4N wave grid, wave tile 64x64
  int row16 = lane & 15, kgl = lane >> 4;

  int bid = blockIdx.x;                        // 1024 blocks, %8==0 -> bijective XCD swizzle
  int swz = (bid & 7) * 128 + (bid >> 3);
  int n = swz >> 7, h0 = swz & 127;
  size_t M0 = (size_t)swz * 128;

  f32x4 acc[4][4];
#pragma unroll
  for (int m = 0; m < 4; ++m)
#pragma unroll
    for (int nf = 0; nf < 4; ++nf) { f32x4 z = {0.f, 0.f, 0.f, 0.f}; acc[m][nf] = z; }

  // A stage: wave w4 -> q=w4>>1, pix=(w4&1)*64+lane. dest = buf + w4*1024 (linear)
  int spixA = (w4 & 1) * 64 + lane;
  const unsigned short* baseA = xt2 + ((size_t)(n * HP + h0) * HP + spixA) * 32 + (w4 >> 1) * 8;
  // B stage: regions r=2*w4+j -> q=r>>2, oc=(r&3)*64+lane. dest = buf+8192+r*1024
  int r0 = 2 * w4, r1 = 2 * w4 + 1;
  const unsigned short* baseB0 = Wt2 + (size_t)((r0 & 3) * 64 + lane) * 32 + (r0 >> 2) * 8;
  const unsigned short* baseB1 = Wt2 + (size_t)((r1 & 3) * 64 + lane) * 32 + (r1 >> 2) * 8;

  auto STAGE = [&](int sv, int b_) {
    int kh_ = sv / 24, rr_ = sv % 24, kw_ = rr_ >> 3, icb_ = rr_ & 7;  // folds (unrolled)
    size_t offA = ((size_t)icb_ * 8 * HP * HP + (size_t)kh_ * HP + kw_) * 32;
    char* buf = lds + b_ * 24576;
    gl16(baseA + offA, buf + w4 * 1024);
    gl16(baseB0 + (size_t)sv * 8192, buf + 8192 + r0 * 1024);
    gl16(baseB1 + (size_t)sv * 8192, buf + 8192 + r1 * 1024);
  };

  STAGE(0, 0); STAGE(1, 1); STAGE(2, 2);

  int aoffA = kgl * 2048 + (wr * 64 + row16) * 16;   // + m*256
  int aoffB = kgl * 4096 + (wc * 64 + row16) * 16;   // + nf*256

#pragma unroll
  for (int s = 0; s < 72; ++s) {
    if (s < 70)      asm volatile("s_waitcnt vmcnt(6)" ::: "memory");
    else if (s == 70) asm volatile("s_waitcnt vmcnt(3)" ::: "memory");
    else             asm volatile("s_waitcnt vmcnt(0)" ::: "memory");
    __builtin_amdgcn_s_barrier();
    __builtin_amdgcn_sched_barrier(0);
    if (s + 3 < 72) STAGE(s + 3, (s + 3) & 3);
    const char* ab = lds + (s & 3) * 24576;
    const char* bb = ab + 8192;
    bf16x8 af[4], bfr[4];
#pragma unroll
    for (int m = 0; m < 4; ++m) af[m] = *(const bf16x8*)(ab + aoffA + m * 256);
#pragma unroll
    for (int nf = 0; nf < 4; ++nf) bfr[nf] = *(const bf16x8*)(bb + aoffB + nf * 256);
    asm volatile("s_waitcnt lgkmcnt(0)" ::: "memory");
    __builtin_amdgcn_sched_barrier(0);
    __builtin_amdgcn_s_setprio(1);
#pragma unroll
    for (int m = 0; m < 4; ++m)
#pragma unroll
      for (int nf = 0; nf < 4; ++nf)
        acc[m][nf] = __builtin_amdgcn_mfma_f32_16x16x32_bf16(af[m], bfr[nf], acc[m][nf], 0, 0, 0);
    __builtin_amdgcn_s_setprio(0);
  }

  // epilogue: bias + mish, store channel-blocked yt2[oc>>5][pix][oc&31], stats
  float sums[4] = {0.f, 0.f, 0.f, 0.f}, sumq[4] = {0.f, 0.f, 0.f, 0.f};
#pragma unroll
  for (int nf = 0; nf < 4; ++nf) {
    int oc = wc * 64 + nf * 16 + row16;
    float bias = b_base[oc];
    size_t obase = (size_t)(oc >> 5) * MPIX * 32 + (oc & 31);
#pragma unroll
    for (int m = 0; m < 4; ++m) {
#pragma unroll
      for (int j = 0; j < 4; ++j) {
        int p = wr * 64 + m * 16 + kgl * 4 + j;
        float y = mishf(acc[m][nf][j] + bias);
        yt2[obase + (M0 + p) * 32] = f2bf(y);
        sums[nf] += y; sumq[nf] += y * y;
      }
    }
  }
#pragma unroll
  for (int nf = 0; nf < 4; ++nf) {
    float s1 = sums[nf], s2 = sumq[nf];
    s1 += __shfl_xor(s1, 16); s2 += __shfl_xor(s2, 16);
    s1 += __shfl_xor(s1, 32); s2 += __shfl_xor(s2, 32);
    if (lane < 16) {
      int oc = wc * 64 + nf * 16 + lane;
      atomicAdd(&statsA[oc], s1);
      atomicAdd(&statsA[256 + oc], s2);
    }
  }
}

// ---------------- K2: finalize base BN, fold into fused 1x1 weights ----------------
// W2t2 layout: [s(8)][64 oc][32] bf16
__global__ __launch_bounds__(256) void k_fold(const float* __restrict__ statsA,
                                              const float* __restrict__ g_base,
                                              const float* __restrict__ be_base,
                                              const float* __restrict__ W_cls,
                                              const float* __restrict__ b_cls,
                                              const float* __restrict__ W_reg,
                                              const float* __restrict__ b_reg,
                                              unsigned short* __restrict__ W2t2,
                                              float* __restrict__ b2) {
  __shared__ float sS[256], sT[256];
  int t = threadIdx.x;
  {
    float cnt = (float)MPIX;
    float m = statsA[t] / cnt;
    float v = fmaxf(statsA[256 + t] / cnt - m * m, 0.f);
    float s = g_base[t] * rsqrtf(v + 1e-5f);
    sS[t] = s;
    sT[t] = be_base[t] - m * s;
  }
  __syncthreads();
  if (t < 64) {
    float bias = 0.f;
    if (t < 36) bias = b_reg[t];
    else if (t < 54) bias = b_cls[t - 36];
    float acc = 0.f;
    for (int ic = 0; ic < 256; ++ic) {
      float w = 0.f;
      if (t < 36) w = W_reg[t * 256 + ic];
      else if (t < 54) w = W_cls[(t - 36) * 256 + ic];
      acc += w * sT[ic];
      W2t2[((size_t)(ic >> 5) * 64 + t) * 32 + (ic & 31)] = f2bf(w * sS[ic]);
    }
    b2[t] = bias + acc;
  }
}

// ---------------- K3: fused 1x1 heads GEMM (M=131072, N=64, K=256) + z stats ----------------
__global__ __launch_bounds__(256) void k_mm2(const unsigned short* __restrict__ yt2,
                                             const unsigned short* __restrict__ W2t2,
                                             const float* __restrict__ b2,
                                             unsigned short* __restrict__ zt,
                                             float* __restrict__ statsZ) {
  __shared__ __align__(16) char lds2[12288];   // A 8KB, B 4KB
  char* a2 = lds2;
  char* b2l = lds2 + 8192;
  int t = threadIdx.x, lane = t & 63, w4 = t >> 6;
  int row16 = lane & 15, kgl = lane >> 4;
  int mq = (row16 & 3) ^ ((row16 >> 2) & 3);
  int kq16 = (kgl ^ mq) * 16;
  size_t pixbase = (size_t)blockIdx.x * 128;

  f32x4 acc[2][4];
#pragma unroll
  for (int m = 0; m < 2; ++m)
#pragma unroll
    for (int nn = 0; nn < 4; ++nn) { f32x4 z = {0.f, 0.f, 0.f, 0.f}; acc[m][nn] = z; }

  int pixA = t >> 2;                           // 0..63 for A-chunk t; +64 for t+256
  int qAa = (t & 3) ^ ((pixA & 3) ^ ((pixA >> 2) & 3));
  char* dA0 = a2 + w4 * 1024;
  char* dA1 = a2 + 4096 + w4 * 1024;
  char* dB = b2l + w4 * 1024;

  for (int s = 0; s < 8; ++s) {
    const unsigned short* pa = yt2 + ((size_t)s * MPIX + pixbase + pixA) * 32 + qAa * 8;
    gl16(pa, dA0);
    gl16(pa + 64 * 32, dA1);                   // pix + 64, same swizzle class
    const unsigned short* pb = W2t2 + ((size_t)s * 64 + pixA) * 32 + qAa * 8;
    gl16(pb, dB);
    __syncthreads();
    bf16x8 af[2], bfr[4];
#pragma unroll
    for (int m = 0; m < 2; ++m)
      af[m] = *(const bf16x8*)(a2 + (w4 * 32 + m * 16 + row16) * 64 + kq16);
#pragma unroll
    for (int nn = 0; nn < 4; ++nn)
      bfr[nn] = *(const bf16x8*)(b2l + (nn * 16 + row16) * 64 + kq16);
#pragma unroll
    for (int m = 0; m < 2; ++m)
#pragma unroll
      for (int nn = 0; nn < 4; ++nn)
        acc[m][nn] = __builtin_amdgcn_mfma_f32_16x16x32_bf16(af[m], bfr[nn], acc[m][nn], 0, 0, 0);
    __syncthreads();
  }

  float sums[4] = {0.f, 0.f, 0.f, 0.f}, sumq[4] = {0.f, 0.f, 0.f, 0.f};
#pragma unroll
  for (int nn = 0; nn < 4; ++nn) {
    int oc = nn * 16 + row16;
    float bias = b2[oc];
#pragma unroll
    for (int m = 0; m < 2; ++m) {
#pragma unroll
      for (int j = 0; j < 4; ++j) {
        int p = w4 * 32 + m * 16 + kgl * 4 + j;
        float v = acc[m][nn][j] + bias;
        zt[(pixbase + p) * 64 + oc] = f2bf(v);
        sums[nn] += v; sumq[nn] += v * v;
      }
    }
  }
#pragma unroll
  for (int nn = 0; nn < 4; ++nn) {
    float s1 = sums[nn], s2 = sumq[nn];
    s1 += __shfl_xor(s1, 16); s2 += __shfl_xor(s2, 16);
    s1 += __shfl_xor(s1, 32); s2 += __shfl_xor(s2, 32);
    if (lane < 16) {
      int oc = nn * 16 + lane;
      atomicAdd(&statsZ[oc], s1);
      atomicAdd(&statsZ[64 + oc], s2);
    }
  }
}

// ---------------- K4: finalize z BN scale/shift ----------------
__global__ __launch_bounds__(64) void k_zstat(const float* __restrict__ statsZ,
                                              const float* __restrict__ g_cls,
                                              const float* __restrict__ be_cls,
                                              const float* __restrict__ g_reg,
                                              const float* __restrict__ be_reg,
                                              float* __restrict__ zsc,
                                              float* __restrict__ zsh) {
  int t = threadIdx.x;  // 64
  float g = 1.f, be = 0.f;
  if (t < 36) { g = g_reg[t]; be = be_reg[t]; }
  else if (t < 54) { g = g_cls[t - 36]; be = be_cls[t - 36]; }
  float cnt = (float)MPIX;
  float m = statsZ[t] / cnt;
  float v = fmaxf(statsZ[64 + t] / cnt - m * m, 0.f);
  float s = g * rsqrtf(v + 1e-5f);
  zsc[t] = s;
  zsh[t] = be - m * s;
}

// ---------------- K5: BN-apply + softmax + anchor decode + outputs ----------------
__global__ __launch_bounds__(256) void k_dec(const unsigned short* __restrict__ zt,
                                             const float* __restrict__ zsc,
                                             const float* __restrict__ zsh,
                                             const int* __restrict__ imgsz,
                                             float* __restrict__ out) {
  int p = blockIdx.x * 256 + threadIdx.x;  // 131072
  float lim = (float)imgsz[0];
  float zn[64];
  {
    const uint4* zp4 = (const uint4*)(zt + (size_t)p * 64);
#pragma unroll
    for (int i = 0; i < 8; ++i) {
      uint4 v = zp4[i];
      unsigned a0 = v.x, a1 = v.y, a2 = v.z, a3 = v.w;
      zn[i * 8 + 0] = bf2f((unsigned short)(a0 & 0xffff));
      zn[i * 8 + 1] = bf2f((unsigned short)(a0 >> 16));
      zn[i * 8 + 2] = bf2f((unsigned short)(a1 & 0xffff));
      zn[i * 8 + 3] = bf2f((unsigned short)(a1 >> 16));
      zn[i * 8 + 4] = bf2f((unsigned short)(a2 & 0xffff));
      zn[i * 8 + 5] = bf2f((unsigned short)(a2 >> 16));
      zn[i * 8 + 6] = bf2f((unsigned short)(a3 & 0xffff));
      zn[i * 8 + 7] = bf2f((unsigned short)(a3 >> 16));
    }
#pragma unroll
    for (int i = 0; i < 54; ++i) zn[i] = zn[i] * zsc[i] + zsh[i];
  }
  int rem = p & 16383, h = rem >> 7, w = rem & 127;
  float fx = 16.f * (float)w, fy = 16.f * (float)h;
  size_t kbase = (size_t)p * 9;
  float* fgout = out;
  float* tsout = out + FGCNT;
  float* roout = out + FGCNT + TSCNT;
#pragma unroll
  for (int a = 0; a < 9; ++a) {
    float x1 = 20.f - 0.5f * AW[a] + fx;
    float y1 = 20.f - 0.5f * AH[a] + fy;
    float x2 = 19.f + 0.5f * AW[a] + fx;
    float y2 = 19.f + 0.5f * AH[a] + fy;
    float cx1 = fminf(fmaxf(x1 + zn[4 * a + 0], 0.f), lim);
    float cy1 = fminf(fmaxf(y1 + zn[4 * a + 1], 0.f), lim);
    float cx2 = fminf(fmaxf(x2 + zn[4 * a + 2], 0.f), lim);
    float cy2 = fminf(fmaxf(y2 + zn[4 * a + 3], 0.f), lim);
    float bw = cx2 - cx1, bh = cy2 - cy1;
    float cx = cx1 + 0.5f * bw, cy = cy1 + 0.5f * bh;
    float aw = AW[a] - 1.f, ah = AH[a] - 1.f;
    float acx = 19.5f + fx, acy = 19.5f + fy;
    float tx = (cx - acx) / aw, ty = (cy - acy) / ah;
    float tw = logf(fmaxf(bw / aw, 1e-30f));
    float th = logf(fmaxf(bh / ah, 1e-30f));
    float s0 = zn[36 + 2 * a], s1 = zn[36 + 2 * a + 1];
    float fg = 1.f / (1.f + expf(s0 - s1));
    fgout[kbase + a] = fg;
    size_t o4 = (kbase + a) * 4;
    tsout[o4 + 0] = tx; tsout[o4 + 1] = ty; tsout[o4 + 2] = tw; tsout[o4 + 3] = th;
    roout[o4 + 0] = cx; roout[o4 + 1] = cy; roout[o4 + 2] = bw; roout[o4 + 3] = bh;
  }
}

// ---------------- launch ----------------
extern "C" void kernel_launch(void* const* d_in, const int* in_sizes, int n_in,
                              void* d_out, int out_size, void* d_ws, size_t ws_size,
                              hipStream_t stream) {
  const float* x   = (const float*)d_in[0];
  const float* Wb  = (const float*)d_in[1];
  const float* bb  = (const float*)d_in[2];
  const float* gb  = (const float*)d_in[3];
  const float* beb = (const float*)d_in[4];
  const float* Wc  = (const float*)d_in[5];
  const float* bc  = (const float*)d_in[6];
  const float* gc  = (const float*)d_in[7];
  const float* bec = (const float*)d_in[8];
  const float* Wr  = (const float*)d_in[9];
  const float* br  = (const float*)d_in[10];
  const float* gr  = (const float*)d_in[11];
  const float* ber = (const float*)d_in[12];
  const int* imgsz = (const int*)d_in[13];

  char* ws = (char*)d_ws;
  const size_t OFF_XTP = 0;                        // 64*130*130*32*2 = 69,222,400
  const size_t OFF_Y   = 69222400;                 // 8*131072*32*2   = 67,108,864
  const size_t OFF_Z   = 136331264;                // 131072*64*2     = 16,777,216
  const size_t OFF_WT  = 153108480;                // 72*256*32*2     =  1,179,648
  const size_t OFF_W2  = 154288128;                // 8*64*32*2       =     32,768
  const size_t OFF_S   = 154320896;                // small area
  unsigned short* xt2  = (unsigned short*)(ws + OFF_XTP);
  unsigned short* yt2  = (unsigned short*)(ws + OFF_Y);
  unsigned short* zt   = (unsigned short*)(ws + OFF_Z);
  unsigned short* Wt2  = (unsigned short*)(ws + OFF_WT);
  unsigned short* W2t2 = (unsigned short*)(ws + OFF_W2);
  float* b2     = (float*)(ws + OFF_S);            // 64 f
  float* statsA = (float*)(ws + OFF_S + 256);      // 512 f
  float* statsZ = (float*)(ws + OFF_S + 2304);     // 128 f
  float* zsc    = (float*)(ws + OFF_S + 2816);     // 64 f
  float* zsh    = (float*)(ws + OFF_S + 3072);     // 64 f
  float* out = (float*)d_out;

  hipMemsetAsync(statsA, 0, (512 + 128) * sizeof(float), stream);
  k_wt  <<<2304, 256, 0, stream>>>(Wb, Wt2);
  k_tr  <<<8192, 256, 0, stream>>>(x, xt2);
  k_bord<<<516, 256, 0, stream>>>(xt2);
  k_conv<<<1024, 512, 0, stream>>>(xt2, Wt2, bb, yt2, statsA);
  k_fold<<<1, 256, 0, stream>>>(statsA, gb, beb, Wc, bc, Wr, br, W2t2, b2);
  k_mm2 <<<1024, 256, 0, stream>>>(yt2, W2t2, b2, zt, statsZ);
  k_zstat<<<1, 64, 0, stream>>>(statsZ, gc, bec, gr, ber, zsc, zsh);
  k_dec <<<512, 256, 0, stream>>>(zt, zsc, zsh, imgsz, out);
}

// Round 7
// 724.847 us; speedup vs baseline: 1.0334x; 1.0334x over previous
//
#include <hip/hip_runtime.h>
#include <stdint.h>

// ---------------- types / helpers ----------------
typedef short bf16x8 __attribute__((ext_vector_type(8)));
typedef float f32x4 __attribute__((ext_vector_type(4)));

#define AS1 __attribute__((address_space(1)))
#define AS3 __attribute__((address_space(3)))

static __device__ __forceinline__ void gl16(const void* g, void* l) {
  __builtin_amdgcn_global_load_lds((const AS1 void*)g, (AS3 void*)l, 16, 0, 0);
}

static __device__ __forceinline__ unsigned short f2bf(float f) {
  unsigned u = __float_as_uint(f);
  u = u + 0x7fffu + ((u >> 16) & 1u);
  return (unsigned short)(u >> 16);
}
static __device__ __forceinline__ float bf2f(unsigned short h) {
  return __uint_as_float(((unsigned)h) << 16);
}
static __device__ __forceinline__ float mishf(float x) {
  float sp = fmaxf(x, 0.f) + log1pf(expf(-fabsf(x)));
  float e2 = expf(-2.f * sp);
  float th = (1.f - e2) / (1.f + e2);
  return x * th;
}

// geometry
#define NIMG 8
#define HH 128
#define WW 128
#define HP 130
#define CIN 256
#define MPIX (NIMG * HH * WW)       // 131072
#define KTOT 2304                   // 72 steps of 32
#define FGCNT (MPIX * 9)            // 1179648
#define TSCNT (MPIX * 9 * 4)        // 4718592

__device__ __constant__ float AW[9] = {456.f, 912.f, 1824.f, 320.f, 640.f, 1280.f, 224.f, 448.f, 896.f};
__device__ __constant__ float AH[9] = {224.f, 448.f, 896.f, 320.f, 640.f, 1280.f, 448.f, 896.f, 1792.f};

// ---------------- K0a: conv weights -> Wt2[s][oc][32] bf16, s = kh*24+kw*8+icb ----------------
__global__ __launch_bounds__(256) void k_wt(const float* __restrict__ Wb,
                                            unsigned short* __restrict__ Wt2) {
  int d = blockIdx.x * 256 + threadIdx.x;  // 589824 = 72*256*32
  int c = d & 31, oc = (d >> 5) & 255, s = d >> 13;
  int kh = s / 24, r = s % 24, kw = r >> 3, icb = r & 7;
  int ic = icb * 32 + c;
  Wt2[d] = f2bf(Wb[((oc * 256 + ic) * 3 + kh) * 3 + kw]);
}

// ---------------- K0b: x (NCHW f32) -> xt2 (channel-blocked padded) interior ----------------
// xt2 layout: [icb(8)*8+n][130][130][32] bf16
__global__ __launch_bounds__(256) void k_tr(const float* __restrict__ x,
                                            unsigned short* __restrict__ xt2) {
  __shared__ float tile[32][129];
  int b = blockIdx.x;  // 8 n * 128 h * 8 icb = 8192
  int icb = b & 7, h = (b >> 3) & 127, n = b >> 10;
  int t = threadIdx.x;
  const float* src = x + (((size_t)(n * 256 + icb * 32) * 128 + h) * 128);
#pragma unroll
  for (int i = 0; i < 4; ++i) {
    int idx = t + 256 * i;          // 1024 float4 units
    int w4 = idx & 31, ic = idx >> 5;
    float4 v = *(const float4*)(src + (size_t)ic * 16384 + w4 * 4);
    tile[ic][w4 * 4 + 0] = v.x; tile[ic][w4 * 4 + 1] = v.y;
    tile[ic][w4 * 4 + 2] = v.z; tile[ic][w4 * 4 + 3] = v.w;
  }
  __syncthreads();
#pragma unroll
  for (int i = 0; i < 8; ++i) {
    int idx = t + 256 * i;          // 2048 bf16-pairs
    int icp = idx & 15, w = idx >> 4;
    unsigned lo = f2bf(tile[icp * 2][w]);
    unsigned hi = f2bf(tile[icp * 2 + 1][w]);
    size_t pix = ((size_t)(icb * 8 + n) * HP + (h + 1)) * HP + (w + 1);
    *(unsigned*)(xt2 + pix * 32 + icp * 2) = lo | (hi << 16);
  }
}

// ---------------- K0c: zero padded borders of xt2 ----------------
__global__ __launch_bounds__(256) void k_bord(unsigned short* __restrict__ xt2) {
  int tid = blockIdx.x * 256 + threadIdx.x;  // 64 planes * 516 border pix * 4 chunks = 132096
  int chunk = tid & 3, pix = tid >> 2;
  int nn = pix / 516, bp = pix % 516;        // nn = icb*8+n plane
  int hp, wp;
  if (bp < 130) { hp = 0; wp = bp; }
  else if (bp < 260) { hp = 129; wp = bp - 130; }
  else { int r = bp - 260; hp = 1 + (r >> 1); wp = (r & 1) ? 129 : 0; }
  size_t off = (((size_t)nn * HP + hp) * HP + wp) * 32 + chunk * 8;
  uint4 z = {0u, 0u, 0u, 0u};
  *(uint4*)(xt2 + off) = z;
}

// ---------------- K1: conv3x3 implicit GEMM ----------------
// M=131072, N=256, K=2304 (72 steps of 32). BM=128 x BN=256, 8 waves, wave tile
// 64x64, acc[4][4]=64 f32/thread (128 spills - R2 lesson).
// LDS layout (per buffer 24KB): region-major, region r = 16 pixels/ocs:
//   byte = r*1024 + q*256 + (idx&15)*16.
// This satisfies ALL THREE constraints (R6 lesson: prior subtile broke source
// coalescing -> 64 lines/gl16 -> 4060 cyc/step):
//   - gl16 dest linear: lane l writes waveRegion + l*16
//   - source coalesced: lane l reads (idx=16r+(l&15), q=l>>4) -> same contig 1KB
//   - ds_read_b128 conflict-free per 8-lane phase: idx16 0..7 x 16B = 128B span
// Pipeline: 4 buffers, depth-3 prefetch, counted vmcnt (6/3/0), one barrier/step.
__global__ __launch_bounds__(512) void k_conv(const unsigned short* __restrict__ xt2,
                                              const unsigned short* __restrict__ Wt2,
                                              const float* __restrict__ b_base,
                                              unsigned short* __restrict__ yt2,
                                              float* __restrict__ statsA) {
  __shared__ __align__(16) char lds[98304];    // 4 x 24KB
  int t = threadIdx.x;
  int lane = t & 63, w4 = t >> 6;              // 8 waves
  int wr = w4 >> 2, wc = w4 & 3;               // 2M x 4N wave grid, wave tile 64x64
  int row16 = lane & 15, kgl = lane >> 4;
  int pr = lane & 15, pq = lane >> 4;          // staging: sub-idx / quarter

  int bid = blockIdx.x;                        // 1024 blocks, %8==0 -> bijective XCD swizzle
  int swz = (bid & 7) * 128 + (bid >> 3);
  int n = swz >> 7, h0 = swz & 127;
  size_t M0 = (size_t)swz * 128;

  f32x4 acc[4][4];
#pragma unroll
  for (int m = 0; m < 4; ++m)
#pragma unroll
    for (int nf = 0; nf < 4; ++nf) { f32x4 z = {0.f, 0.f, 0.f, 0.f}; acc[m][nf] = z; }

  // A: wave w4 stages region w4 (pixels 16*w4 .. +15), lane -> (pix=16w4+pr, q=pq)
  const unsigned short* baseA =
      xt2 + ((size_t)(n * HP + h0) * HP + w4 * 16 + pr) * 32 + pq * 8;
  // B: wave w4 stages regions 2w4, 2w4+1 (ocs 32w4..32w4+31)
  const unsigned short* baseB0 = Wt2 + (size_t)(w4 * 32 + pr) * 32 + pq * 8;
  const unsigned short* baseB1 = Wt2 + (size_t)(w4 * 32 + 16 + pr) * 32 + pq * 8;

  auto STAGE = [&](int sv, int b_) {
    int kh_ = sv / 24, rr_ = sv % 24, kw_ = rr_ >> 3, icb_ = rr_ & 7;  // folds (unrolled)
    size_t offA = ((size_t)icb_ * 8 * HP * HP + (size_t)kh_ * HP + kw_) * 32;
    size_t offB = (size_t)sv * 8192;
    char* buf = lds + b_ * 24576;
    gl16(baseA + offA, buf + w4 * 1024);
    gl16(baseB0 + offB, buf + 8192 + (2 * w4) * 1024);
    gl16(baseB1 + offB, buf + 8192 + (2 * w4 + 1) * 1024);
  };

  STAGE(0, 0); STAGE(1, 1); STAGE(2, 2);

  int aoffA = wr * 4096 + kgl * 256 + row16 * 16;   // + m*1024
  int aoffB = wc * 4096 + kgl * 256 + row16 * 16;   // + nf*1024

#pragma unroll
  for (int s = 0; s < 72; ++s) {
    if (s < 70)       asm volatile("s_waitcnt vmcnt(6)" ::: "memory");
    else if (s == 70) asm volatile("s_waitcnt vmcnt(3)" ::: "memory");
    else              asm volatile("s_waitcnt vmcnt(0)" ::: "memory");
    __builtin_amdgcn_s_barrier();
    __builtin_amdgcn_sched_barrier(0);
    if (s + 3 < 72) STAGE(s + 3, (s + 3) & 3);
    const char* ab = lds + (s & 3) * 24576;
    const char* bb = ab + 8192;
    bf16x8 af[4], bfr[4];
#pragma unroll
    for (int m = 0; m < 4; ++m) af[m] = *(const bf16x8*)(ab + aoffA + m * 1024);
#pragma unroll
    for (int nf = 0; nf < 4; ++nf) bfr[nf] = *(const bf16x8*)(bb + aoffB + nf * 1024);
    asm volatile("s_waitcnt lgkmcnt(0)" ::: "memory");
    __builtin_amdgcn_sched_barrier(0);
#pragma unroll
    for (int m = 0; m < 4; ++m)
#pragma unroll
      for (int nf = 0; nf < 4; ++nf)
        acc[m][nf] = __builtin_amdgcn_mfma_f32_16x16x32_bf16(af[m], bfr[nf], acc[m][nf], 0, 0, 0);
  }

  // epilogue: bias + mish, store channel-blocked yt2[oc>>5][pix][oc&31], stats
  float sums[4] = {0.f, 0.f, 0.f, 0.f}, sumq[4] = {0.f, 0.f, 0.f, 0.f};
#pragma unroll
  for (int nf = 0; nf < 4; ++nf) {
    int oc = wc * 64 + nf * 16 + row16;
    float bias = b_base[oc];
    size_t obase = (size_t)(oc >> 5) * MPIX * 32 + (oc & 31);
#pragma unroll
    for (int m = 0; m < 4; ++m) {
#pragma unroll
      for (int j = 0; j < 4; ++j) {
        int p = wr * 64 + m * 16 + kgl * 4 + j;
        float y = mishf(acc[m][nf][j] + bias);
        yt2[obase + (M0 + p) * 32] = f2bf(y);
        sums[nf] += y; sumq[nf] += y * y;
      }
    }
  }
#pragma unroll
  for (int nf = 0; nf < 4; ++nf) {
    float s1 = sums[nf], s2 = sumq[nf];
    s1 += __shfl_xor(s1, 16); s2 += __shfl_xor(s2, 16);
    s1 += __shfl_xor(s1, 32); s2 += __shfl_xor(s2, 32);
    if (lane < 16) {
      int oc = wc * 64 + nf * 16 + lane;
      atomicAdd(&statsA[oc], s1);
      atomicAdd(&statsA[256 + oc], s2);
    }
  }
}

// ---------------- K2: finalize base BN, fold into fused 1x1 weights ----------------
// W2t2 layout: [s(8)][64 oc][32] bf16
__global__ __launch_bounds__(256) void k_fold(const float* __restrict__ statsA,
                                              const float* __restrict__ g_base,
                                              const float* __restrict__ be_base,
                                              const float* __restrict__ W_cls,
                                              const float* __restrict__ b_cls,
                                              const float* __restrict__ W_reg,
                                              const float* __restrict__ b_reg,
                                              unsigned short* __restrict__ W2t2,
                                              float* __restrict__ b2) {
  __shared__ float sS[256], sT[256];
  int t = threadIdx.x;
  {
    float cnt = (float)MPIX;
    float m = statsA[t] / cnt;
    float v = fmaxf(statsA[256 + t] / cnt - m * m, 0.f);
    float s = g_base[t] * rsqrtf(v + 1e-5f);
    sS[t] = s;
    sT[t] = be_base[t] - m * s;
  }
  __syncthreads();
  if (t < 64) {
    float bias = 0.f;
    if (t < 36) bias = b_reg[t];
    else if (t < 54) bias = b_cls[t - 36];
    float acc = 0.f;
    for (int ic = 0; ic < 256; ++ic) {
      float w = 0.f;
      if (t < 36) w = W_reg[t * 256 + ic];
      else if (t < 54) w = W_cls[(t - 36) * 256 + ic];
      acc += w * sT[ic];
      W2t2[((size_t)(ic >> 5) * 64 + t) * 32 + (ic & 31)] = f2bf(w * sS[ic]);
    }
    b2[t] = bias + acc;
  }
}

// ---------------- K3: fused 1x1 heads GEMM (M=131072, N=64, K=256) + z stats ----------------
// Same region-major LDS layout as k_conv; 2-buffer dbuf, stage hidden under MFMA.
__global__ __launch_bounds__(256) void k_mm2(const unsigned short* __restrict__ yt2,
                                             const unsigned short* __restrict__ W2t2,
                                             const float* __restrict__ b2,
                                             unsigned short* __restrict__ zt,
                                             float* __restrict__ statsZ) {
  __shared__ __align__(16) char lds2[24576];   // 2 x (A 8KB + B 4KB)
  int t = threadIdx.x, lane = t & 63, w4 = t >> 6;   // 4 waves
  int row16 = lane & 15, kgl = lane >> 4;
  int pr = lane & 15, pq = lane >> 4;
  size_t pixbase = (size_t)blockIdx.x * 128;

  f32x4 acc[2][4];
#pragma unroll
  for (int m = 0; m < 2; ++m)
#pragma unroll
    for (int nn = 0; nn < 4; ++nn) { f32x4 z = {0.f, 0.f, 0.f, 0.f}; acc[m][nn] = z; }

  // A: wave w4 stages regions 2w4, 2w4+1 (pixels 32w4 .. +31)
  const unsigned short* aSrc0 = yt2 + (pixbase + w4 * 32 + pr) * 32 + pq * 8;
  const unsigned short* aSrc1 = yt2 + (pixbase + w4 * 32 + 16 + pr) * 32 + pq * 8;
  // B: wave w4 stages region w4 (ocs 16w4 .. +15)
  const unsigned short* bSrc = W2t2 + (size_t)(w4 * 16 + pr) * 32 + pq * 8;
  char* dA0 = lds2 + (2 * w4) * 1024;
  char* dA1 = lds2 + (2 * w4 + 1) * 1024;
  char* dB  = lds2 + 8192 + w4 * 1024;

  auto STG = [&](int s, int b_) {
    size_t ao = (size_t)s * MPIX * 32;
    size_t bo = (size_t)s * 2048;          // 64 oc * 32
    gl16(aSrc0 + ao, dA0 + b_ * 12288);
    gl16(aSrc1 + ao, dA1 + b_ * 12288);
    gl16(bSrc + bo, dB + b_ * 12288);
  };

  STG(0, 0);
  asm volatile("s_waitcnt vmcnt(0)" ::: "memory");
  __builtin_amdgcn_s_barrier();
  __builtin_amdgcn_sched_barrier(0);

  int aoffA = w4 * 2048 + kgl * 256 + row16 * 16;  // region w4*2+m -> + m*1024
  int aoffB = kgl * 256 + row16 * 16;              // region nf -> + nf*1024

#pragma unroll
  for (int s = 0; s < 8; ++s) {
    if (s < 7) STG(s + 1, (s + 1) & 1);
    const char* ab = lds2 + (s & 1) * 12288;
    const char* bb = ab + 8192;
    bf16x8 af[2], bfr[4];
#pragma unroll
    for (int m = 0; m < 2; ++m) af[m] = *(const bf16x8*)(ab + aoffA + m * 1024);
#pragma unroll
    for (int nn = 0; nn < 4; ++nn) bfr[nn] = *(const bf16x8*)(bb + aoffB + nn * 1024);
    asm volatile("s_waitcnt lgkmcnt(0)" ::: "memory");
    __builtin_amdgcn_sched_barrier(0);
#pragma unroll
    for (int m = 0; m < 2; ++m)
#pragma unroll
      for (int nn = 0; nn < 4; ++nn)
        acc[m][nn] = __builtin_amdgcn_mfma_f32_16x16x32_bf16(af[m], bfr[nn], acc[m][nn], 0, 0, 0);
    if (s < 7) {
      asm volatile("s_waitcnt vmcnt(0)" ::: "memory");
      __builtin_amdgcn_s_barrier();
      __builtin_amdgcn_sched_barrier(0);
    }
  }

  float sums[4] = {0.f, 0.f, 0.f, 0.f}, sumq[4] = {0.f, 0.f, 0.f, 0.f};
#pragma unroll
  for (int nn = 0; nn < 4; ++nn) {
    int oc = nn * 16 + row16;
    float bias = b2[oc];
#pragma unroll
    for (int m = 0; m < 2; ++m) {
#pragma unroll
      for (int j = 0; j < 4; ++j) {
        int p = w4 * 32 + m * 16 + kgl * 4 + j;
        float v = acc[m][nn][j] + bias;
        zt[(pixbase + p) * 64 + oc] = f2bf(v);
        sums[nn] += v; sumq[nn] += v * v;
      }
    }
  }
#pragma unroll
  for (int nn = 0; nn < 4; ++nn) {
    float s1 = sums[nn], s2 = sumq[nn];
    s1 += __shfl_xor(s1, 16); s2 += __shfl_xor(s2, 16);
    s1 += __shfl_xor(s1, 32); s2 += __shfl_xor(s2, 32);
    if (lane < 16) {
      int oc = nn * 16 + lane;
      atomicAdd(&statsZ[oc], s1);
      atomicAdd(&statsZ[64 + oc], s2);
    }
  }
}

// ---------------- K4: finalize z BN scale/shift ----------------
__global__ __launch_bounds__(64) void k_zstat(const float* __restrict__ statsZ,
                                              const float* __restrict__ g_cls,
                                              const float* __restrict__ be_cls,
                                              const float* __restrict__ g_reg,
                                              const float* __restrict__ be_reg,
                                              float* __restrict__ zsc,
                                              float* __restrict__ zsh) {
  int t = threadIdx.x;  // 64
  float g = 1.f, be = 0.f;
  if (t < 36) { g = g_reg[t]; be = be_reg[t]; }
  else if (t < 54) { g = g_cls[t - 36]; be = be_cls[t - 36]; }
  float cnt = (float)MPIX;
  float m = statsZ[t] / cnt;
  float v = fmaxf(statsZ[64 + t] / cnt - m * m, 0.f);
  float s = g * rsqrtf(v + 1e-5f);
  zsc[t] = s;
  zsh[t] = be - m * s;
}

// ---------------- K5: BN-apply + softmax + anchor decode + outputs ----------------
__global__ __launch_bounds__(256) void k_dec(const unsigned short* __restrict__ zt,
                                             const float* __restrict__ zsc,
                                             const float* __restrict__ zsh,
                                             const int* __restrict__ imgsz,
                                             float* __restrict__ out) {
  int p = blockIdx.x * 256 + threadIdx.x;  // 131072
  float lim = (float)imgsz[0];
  float zn[64];
  {
    const uint4* zp4 = (const uint4*)(zt + (size_t)p * 64);
#pragma unroll
    for (int i = 0; i < 8; ++i) {
      uint4 v = zp4[i];
      unsigned a0 = v.x, a1 = v.y, a2 = v.z, a3 = v.w;
      zn[i * 8 + 0] = bf2f((unsigned short)(a0 & 0xffff));
      zn[i * 8 + 1] = bf2f((unsigned short)(a0 >> 16));
      zn[i * 8 + 2] = bf2f((unsigned short)(a1 & 0xffff));
      zn[i * 8 + 3] = bf2f((unsigned short)(a1 >> 16));
      zn[i * 8 + 4] = bf2f((unsigned short)(a2 & 0xffff));
      zn[i * 8 + 5] = bf2f((unsigned short)(a2 >> 16));
      zn[i * 8 + 6] = bf2f((unsigned short)(a3 & 0xffff));
      zn[i * 8 + 7] = bf2f((unsigned short)(a3 >> 16));
    }
#pragma unroll
    for (int i = 0; i < 54; ++i) zn[i] = zn[i] * zsc[i] + zsh[i];
  }
  int rem = p & 16383, h = rem >> 7, w = rem & 127;
  float fx = 16.f * (float)w, fy = 16.f * (float)h;
  size_t kbase = (size_t)p * 9;
  float* fgout = out;
  float* tsout = out + FGCNT;
  float* roout = out + FGCNT + TSCNT;
#pragma unroll
  for (int a = 0; a < 9; ++a) {
    float x1 = 20.f - 0.5f * AW[a] + fx;
    float y1 = 20.f - 0.5f * AH[a] + fy;
    float x2 = 19.f + 0.5f * AW[a] + fx;
    float y2 = 19.f + 0.5f * AH[a] + fy;
    float cx1 = fminf(fmaxf(x1 + zn[4 * a + 0], 0.f), lim);
    float cy1 = fminf(fmaxf(y1 + zn[4 * a + 1], 0.f), lim);
    float cx2 = fminf(fmaxf(x2 + zn[4 * a + 2], 0.f), lim);
    float cy2 = fminf(fmaxf(y2 + zn[4 * a + 3], 0.f), lim);
    float bw = cx2 - cx1, bh = cy2 - cy1;
    float cx = cx1 + 0.5f * bw, cy = cy1 + 0.5f * bh;
    float aw = AW[a] - 1.f, ah = AH[a] - 1.f;
    float acx = 19.5f + fx, acy = 19.5f + fy;
    float tx = (cx - acx) / aw, ty = (cy - acy) / ah;
    float tw = logf(fmaxf(bw / aw, 1e-30f));
    float th = logf(fmaxf(bh / ah, 1e-30f));
    float s0 = zn[36 + 2 * a], s1 = zn[36 + 2 * a + 1];
    float fg = 1.f / (1.f + expf(s0 - s1));
    fgout[kbase + a] = fg;
    size_t o4 = (kbase + a) * 4;
    tsout[o4 + 0] = tx; tsout[o4 + 1] = ty; tsout[o4 + 2] = tw; tsout[o4 + 3] = th;
    roout[o4 + 0] = cx; roout[o4 + 1] = cy; roout[o4 + 2] = bw; roout[o4 + 3] = bh;
  }
}

// ---------------- launch ----------------
extern "C" void kernel_launch(void* const* d_in, const int* in_sizes, int n_in,
                              void* d_out, int out_size, void* d_ws, size_t ws_size,
                              hipStream_t stream) {
  const float* x   = (const float*)d_in[0];
  const float* Wb  = (const float*)d_in[1];
  const float* bb  = (const float*)d_in[2];
  const float* gb  = (const float*)d_in[3];
  const float* beb = (const float*)d_in[4];
  const float* Wc  = (const float*)d_in[5];
  const float* bc  = (const float*)d_in[6];
  const float* gc  = (const float*)d_in[7];
  const float* bec = (const float*)d_in[8];
  const float* Wr  = (const float*)d_in[9];
  const float* br  = (const float*)d_in[10];
  const float* gr  = (const float*)d_in[11];
  const float* ber = (const float*)d_in[12];
  const int* imgsz = (const int*)d_in[13];

  char* ws = (char*)d_ws;
  const size_t OFF_XTP = 0;                        // 64*130*130*32*2 = 69,222,400
  const size_t OFF_Y   = 69222400;                 // 8*131072*32*2   = 67,108,864
  const size_t OFF_Z   = 136331264;                // 131072*64*2     = 16,777,216
  const size_t OFF_WT  = 153108480;                // 72*256*32*2     =  1,179,648
  const size_t OFF_W2  = 154288128;                // 8*64*32*2       =     32,768
  const size_t OFF_S   = 154320896;                // small area
  unsigned short* xt2  = (unsigned short*)(ws + OFF_XTP);
  unsigned short* yt2  = (unsigned short*)(ws + OFF_Y);
  unsigned short* zt   = (unsigned short*)(ws + OFF_Z);
  unsigned short* Wt2  = (unsigned short*)(ws + OFF_WT);
  unsigned short* W2t2 = (unsigned short*)(ws + OFF_W2);
  float* b2     = (float*)(ws + OFF_S);            // 64 f
  float* statsA = (float*)(ws + OFF_S + 256);      // 512 f
  float* statsZ = (float*)(ws + OFF_S + 2304);     // 128 f
  float* zsc    = (float*)(ws + OFF_S + 2816);     // 64 f
  float* zsh    = (float*)(ws + OFF_S + 3072);     // 64 f
  float* out = (float*)d_out;

  hipMemsetAsync(statsA, 0, (512 + 128) * sizeof(float), stream);
  k_wt  <<<2304, 256, 0, stream>>>(Wb, Wt2);
  k_tr  <<<8192, 256, 0, stream>>>(x, xt2);
  k_bord<<<516, 256, 0, stream>>>(xt2);
  k_conv<<<1024, 512, 0, stream>>>(xt2, Wt2, bb, yt2, statsA);
  k_fold<<<1, 256, 0, stream>>>(statsA, gb, beb, Wc, bc, Wr, br, W2t2, b2);
  k_mm2 <<<1024, 256, 0, stream>>>(yt2, W2t2, b2, zt, statsZ);
  k_zstat<<<1, 64, 0, stream>>>(statsZ, gc, bec, gr, ber, zsc, zsh);
  k_dec <<<512, 256, 0, stream>>>(zt, zsc, zsh, imgsz, out);
}

// Round 8
// 546.503 us; speedup vs baseline: 1.3707x; 1.3263x over previous
//
#include <hip/hip_runtime.h>
#include <stdint.h>

// ---------------- types / helpers ----------------
typedef short bf16x8 __attribute__((ext_vector_type(8)));
typedef float f32x4 __attribute__((ext_vector_type(4)));

#define AS1 __attribute__((address_space(1)))
#define AS3 __attribute__((address_space(3)))

static __device__ __forceinline__ void gl16(const void* g, void* l) {
  __builtin_amdgcn_global_load_lds((const AS1 void*)g, (AS3 void*)l, 16, 0, 0);
}

static __device__ __forceinline__ unsigned short f2bf(float f) {
  unsigned u = __float_as_uint(f);
  u = u + 0x7fffu + ((u >> 16) & 1u);
  return (unsigned short)(u >> 16);
}
static __device__ __forceinline__ float bf2f(unsigned short h) {
  return __uint_as_float(((unsigned)h) << 16);
}
static __device__ __forceinline__ float mishf(float x) {
  float sp = fmaxf(x, 0.f) + log1pf(expf(-fabsf(x)));
  float e2 = expf(-2.f * sp);
  float th = (1.f - e2) / (1.f + e2);
  return x * th;
}

// geometry
#define NIMG 8
#define HH 128
#define WW 128
#define HP 130
#define CIN 256
#define MPIX (NIMG * HH * WW)       // 131072
#define KTOT 2304                   // 72 steps of 32
#define FGCNT (MPIX * 9)            // 1179648
#define TSCNT (MPIX * 9 * 4)        // 4718592

__device__ __constant__ float AW[9] = {456.f, 912.f, 1824.f, 320.f, 640.f, 1280.f, 224.f, 448.f, 896.f};
__device__ __constant__ float AH[9] = {224.f, 448.f, 896.f, 320.f, 640.f, 1280.f, 448.f, 896.f, 1792.f};

// ---------------- K0a: conv weights -> Wt2[s][oc][32] bf16, s = kh*24+kw*8+icb ----------------
__global__ __launch_bounds__(256) void k_wt(const float* __restrict__ Wb,
                                            unsigned short* __restrict__ Wt2) {
  int d = blockIdx.x * 256 + threadIdx.x;  // 589824 = 72*256*32
  int c = d & 31, oc = (d >> 5) & 255, s = d >> 13;
  int kh = s / 24, r = s % 24, kw = r >> 3, icb = r & 7;
  int ic = icb * 32 + c;
  Wt2[d] = f2bf(Wb[((oc * 256 + ic) * 3 + kh) * 3 + kw]);
}

// ---------------- K0b: x (NCHW f32) -> xt2 (channel-blocked padded) interior ----------------
// xt2 layout: [icb(8)*8+n][130][130][32] bf16
__global__ __launch_bounds__(256) void k_tr(const float* __restrict__ x,
                                            unsigned short* __restrict__ xt2) {
  __shared__ float tile[32][129];
  int b = blockIdx.x;  // 8 n * 128 h * 8 icb = 8192
  int icb = b & 7, h = (b >> 3) & 127, n = b >> 10;
  int t = threadIdx.x;
  const float* src = x + (((size_t)(n * 256 + icb * 32) * 128 + h) * 128);
#pragma unroll
  for (int i = 0; i < 4; ++i) {
    int idx = t + 256 * i;          // 1024 float4 units
    int w4 = idx & 31, ic = idx >> 5;
    float4 v = *(const float4*)(src + (size_t)ic * 16384 + w4 * 4);
    tile[ic][w4 * 4 + 0] = v.x; tile[ic][w4 * 4 + 1] = v.y;
    tile[ic][w4 * 4 + 2] = v.z; tile[ic][w4 * 4 + 3] = v.w;
  }
  __syncthreads();
#pragma unroll
  for (int i = 0; i < 8; ++i) {
    int idx = t + 256 * i;          // 2048 bf16-pairs
    int icp = idx & 15, w = idx >> 4;
    unsigned lo = f2bf(tile[icp * 2][w]);
    unsigned hi = f2bf(tile[icp * 2 + 1][w]);
    size_t pix = ((size_t)(icb * 8 + n) * HP + (h + 1)) * HP + (w + 1);
    *(unsigned*)(xt2 + pix * 32 + icp * 2) = lo | (hi << 16);
  }
}

// ---------------- K0c: zero padded borders of xt2 ----------------
__global__ __launch_bounds__(256) void k_bord(unsigned short* __restrict__ xt2) {
  int tid = blockIdx.x * 256 + threadIdx.x;  // 64 planes * 516 border pix * 4 chunks = 132096
  int chunk = tid & 3, pix = tid >> 2;
  int nn = pix / 516, bp = pix % 516;        // nn = icb*8+n plane
  int hp, wp;
  if (bp < 130) { hp = 0; wp = bp; }
  else if (bp < 260) { hp = 129; wp = bp - 130; }
  else { int r = bp - 260; hp = 1 + (r >> 1); wp = (r & 1) ? 129 : 0; }
  size_t off = (((size_t)nn * HP + hp) * HP + wp) * 32 + chunk * 8;
  uint4 z = {0u, 0u, 0u, 0u};
  *(uint4*)(xt2 + off) = z;
}

// ---------------- K1: conv3x3 implicit GEMM — m97 structure ----------------
// M=131072, N=256, K=2304. BM=128 (one row) x BN=128 (oc half), 4 waves, wave
// tile 64x64, acc[4][4]. 16KB single-buffer LDS, plain __syncthreads 2-barrier
// loop, COMPILER-scheduled (R6/R7 lesson = m141: asm waitcnt + sched_barrier
// pinning regresses ~40%; m114: ~3 blocks/CU cross-block overlap is what hides
// the staging drain -- needs <=~150 regs/thread, so 4-wave blocks, not 8).
// LDS region-major (R7, 0-conflict): byte = region*1024 + q*256 + (idx&15)*16;
// gl16 dest linear per wave region, source contiguous 1KB per wave.
// Grid 2048 = 1024 pixblocks x 2 oc-halves; bijective XCD swizzle keeps both
// halves + neighboring rows of a pixblock on one XCD (A rows L2-local).
__global__ __launch_bounds__(256) void k_conv(const unsigned short* __restrict__ xt2,
                                              const unsigned short* __restrict__ Wt2,
                                              const float* __restrict__ b_base,
                                              unsigned short* __restrict__ yt2,
                                              float* __restrict__ statsA) {
  __shared__ __align__(16) char lds[16384];    // A 8KB | B 8KB
  int t = threadIdx.x;
  int lane = t & 63, w4 = t >> 6;              // 4 waves
  int wr = w4 >> 1, wc = w4 & 1;               // 2M x 2N wave grid, wave tile 64x64
  int row16 = lane & 15, kgl = lane >> 4;
  int pr = lane & 15, pq = lane >> 4;          // staging lane decomposition

  int bid = blockIdx.x;                        // 2048, %8==0 -> bijective
  int swz = (bid & 7) * 256 + (bid >> 3);      // XCD k owns contiguous 256 tiles
  int pixb = swz >> 1, oh = swz & 1;
  int n = pixb >> 7, h0 = pixb & 127;
  size_t M0 = (size_t)pixb * 128;

  f32x4 acc[4][4];
#pragma unroll
  for (int m = 0; m < 4; ++m)
#pragma unroll
    for (int nf = 0; nf < 4; ++nf) { f32x4 z = {0.f, 0.f, 0.f, 0.f}; acc[m][nf] = z; }

  // A: wave w4 stages regions 2w4, 2w4+1 (pixels 32w4 .. +31)
  const unsigned short* aS0 =
      xt2 + ((size_t)(n * HP + h0) * HP + w4 * 32 + pr) * 32 + pq * 8;
  const unsigned short* aS1 = aS0 + 16 * 32;
  // B: wave w4 stages regions 2w4, 2w4+1 (ocs oh*128 + 32w4 .. +31)
  const unsigned short* bS0 = Wt2 + (size_t)(oh * 128 + w4 * 32 + pr) * 32 + pq * 8;
  const unsigned short* bS1 = bS0 + 16 * 32;
  char* dA0 = lds + (2 * w4) * 1024;
  char* dA1 = lds + (2 * w4 + 1) * 1024;
  char* dB0 = lds + 8192 + (2 * w4) * 1024;
  char* dB1 = lds + 8192 + (2 * w4 + 1) * 1024;

  int aoffA = wr * 4096 + kgl * 256 + row16 * 16;   // + m*1024
  int aoffB = wc * 4096 + kgl * 256 + row16 * 16;   // + nf*1024
  const size_t planeStride = (size_t)8 * HP * HP * 32;

  int s = 0;
  for (int kh = 0; kh < 3; ++kh) {
    for (int kw = 0; kw < 3; ++kw) {
      for (int icb = 0; icb < 8; ++icb, ++s) {
        size_t offA = (size_t)icb * planeStride + ((size_t)kh * HP + kw) * 32;
        size_t offB = (size_t)s * 8192;      // 256 oc * 32 shorts per k-step
        gl16(aS0 + offA, dA0);
        gl16(aS1 + offA, dA1);
        gl16(bS0 + offB, dB0);
        gl16(bS1 + offB, dB1);
        __syncthreads();
        bf16x8 af[4], bfr[4];
#pragma unroll
        for (int m = 0; m < 4; ++m) af[m] = *(const bf16x8*)(lds + aoffA + m * 1024);
#pragma unroll
        for (int nf = 0; nf < 4; ++nf) bfr[nf] = *(const bf16x8*)(lds + 8192 + aoffB + nf * 1024);
#pragma unroll
        for (int m = 0; m < 4; ++m)
#pragma unroll
          for (int nf = 0; nf < 4; ++nf)
            acc[m][nf] = __builtin_amdgcn_mfma_f32_16x16x32_bf16(af[m], bfr[nf], acc[m][nf], 0, 0, 0);
        __syncthreads();
      }
    }
  }

  // epilogue: bias + mish, store channel-blocked yt2[oc>>5][pix][oc&31], stats
  float sums[4] = {0.f, 0.f, 0.f, 0.f}, sumq[4] = {0.f, 0.f, 0.f, 0.f};
#pragma unroll
  for (int nf = 0; nf < 4; ++nf) {
    int oc = oh * 128 + wc * 64 + nf * 16 + row16;
    float bias = b_base[oc];
    size_t obase = (size_t)(oc >> 5) * MPIX * 32 + (oc & 31);
#pragma unroll
    for (int m = 0; m < 4; ++m) {
#pragma unroll
      for (int j = 0; j < 4; ++j) {
        int p = wr * 64 + m * 16 + kgl * 4 + j;
        float y = mishf(acc[m][nf][j] + bias);
        yt2[obase + (M0 + p) * 32] = f2bf(y);
        sums[nf] += y; sumq[nf] += y * y;
      }
    }
  }
#pragma unroll
  for (int nf = 0; nf < 4; ++nf) {
    float s1 = sums[nf], s2 = sumq[nf];
    s1 += __shfl_xor(s1, 16); s2 += __shfl_xor(s2, 16);
    s1 += __shfl_xor(s1, 32); s2 += __shfl_xor(s2, 32);
    if (lane < 16) {
      int oc = oh * 128 + wc * 64 + nf * 16 + lane;
      atomicAdd(&statsA[oc], s1);
      atomicAdd(&statsA[256 + oc], s2);
    }
  }
}

// ---------------- K2: finalize base BN, fold into fused 1x1 weights ----------------
// W2t2 layout: [s(8)][64 oc][32] bf16
__global__ __launch_bounds__(256) void k_fold(const float* __restrict__ statsA,
                                              const float* __restrict__ g_base,
                                              const float* __restrict__ be_base,
                                              const float* __restrict__ W_cls,
                                              const float* __restrict__ b_cls,
                                              const float* __restrict__ W_reg,
                                              const float* __restrict__ b_reg,
                                              unsigned short* __restrict__ W2t2,
                                              float* __restrict__ b2) {
  __shared__ float sS[256], sT[256];
  int t = threadIdx.x;
  {
    float cnt = (float)MPIX;
    float m = statsA[t] / cnt;
    float v = fmaxf(statsA[256 + t] / cnt - m * m, 0.f);
    float s = g_base[t] * rsqrtf(v + 1e-5f);
    sS[t] = s;
    sT[t] = be_base[t] - m * s;
  }
  __syncthreads();
  if (t < 64) {
    float bias = 0.f;
    if (t < 36) bias = b_reg[t];
    else if (t < 54) bias = b_cls[t - 36];
    float acc = 0.f;
    for (int ic = 0; ic < 256; ++ic) {
      float w = 0.f;
      if (t < 36) w = W_reg[t * 256 + ic];
      else if (t < 54) w = W_cls[(t - 36) * 256 + ic];
      acc += w * sT[ic];
      W2t2[((size_t)(ic >> 5) * 64 + t) * 32 + (ic & 31)] = f2bf(w * sS[ic]);
    }
    b2[t] = bias + acc;
  }
}

// ---------------- K3: fused 1x1 heads GEMM (M=131072, N=64, K=256) + z stats ----------------
// Same region-major LDS + plain 2-barrier loop. 4 waves; wave w4 owns pixels
// 32w4..+31 (acc[2][4]). 12KB single buffer.
__global__ __launch_bounds__(256) void k_mm2(const unsigned short* __restrict__ yt2,
                                             const unsigned short* __restrict__ W2t2,
                                             const float* __restrict__ b2,
                                             unsigned short* __restrict__ zt,
                                             float* __restrict__ statsZ) {
  __shared__ __align__(16) char lds2[12288];   // A 8KB | B 4KB
  int t = threadIdx.x, lane = t & 63, w4 = t >> 6;   // 4 waves
  int row16 = lane & 15, kgl = lane >> 4;
  int pr = lane & 15, pq = lane >> 4;
  size_t pixbase = (size_t)blockIdx.x * 128;

  f32x4 acc[2][4];
#pragma unroll
  for (int m = 0; m < 2; ++m)
#pragma unroll
    for (int nn = 0; nn < 4; ++nn) { f32x4 z = {0.f, 0.f, 0.f, 0.f}; acc[m][nn] = z; }

  // A: wave w4 stages regions 2w4, 2w4+1 (pixels 32w4 .. +31)
  const unsigned short* aS0 = yt2 + (pixbase + w4 * 32 + pr) * 32 + pq * 8;
  const unsigned short* aS1 = aS0 + 16 * 32;
  // B: wave w4 stages region w4 (ocs 16w4 .. +15)
  const unsigned short* bS = W2t2 + (size_t)(w4 * 16 + pr) * 32 + pq * 8;
  char* dA0 = lds2 + (2 * w4) * 1024;
  char* dA1 = lds2 + (2 * w4 + 1) * 1024;
  char* dB  = lds2 + 8192 + w4 * 1024;

  int aoffA = w4 * 2048 + kgl * 256 + row16 * 16;  // + m*1024
  int aoffB = kgl * 256 + row16 * 16;              // + nn*1024

  for (int s = 0; s < 8; ++s) {
    size_t ao = (size_t)s * MPIX * 32;
    size_t bo = (size_t)s * 2048;          // 64 oc * 32
    gl16(aS0 + ao, dA0);
    gl16(aS1 + ao, dA1);
    gl16(bS + bo, dB);
    __syncthreads();
    bf16x8 af[2], bfr[4];
#pragma unroll
    for (int m = 0; m < 2; ++m) af[m] = *(const bf16x8*)(lds2 + aoffA + m * 1024);
#pragma unroll
    for (int nn = 0; nn < 4; ++nn) bfr[nn] = *(const bf16x8*)(lds2 + 8192 + aoffB + nn * 1024);
#pragma unroll
    for (int m = 0; m < 2; ++m)
#pragma unroll
      for (int nn = 0; nn < 4; ++nn)
        acc[m][nn] = __builtin_amdgcn_mfma_f32_16x16x32_bf16(af[m], bfr[nn], acc[m][nn], 0, 0, 0);
    __syncthreads();
  }

  float sums[4] = {0.f, 0.f, 0.f, 0.f}, sumq[4] = {0.f, 0.f, 0.f, 0.f};
#pragma unroll
  for (int nn = 0; nn < 4; ++nn) {
    int oc = nn * 16 + row16;
    float bias = b2[oc];
#pragma unroll
    for (int m = 0; m < 2; ++m) {
#pragma unroll
      for (int j = 0; j < 4; ++j) {
        int p = w4 * 32 + m * 16 + kgl * 4 + j;
        float v = acc[m][nn][j] + bias;
        zt[(pixbase + p) * 64 + oc] = f2bf(v);
        sums[nn] += v; sumq[nn] += v * v;
      }
    }
  }
#pragma unroll
  for (int nn = 0; nn < 4; ++nn) {
    float s1 = sums[nn], s2 = sumq[nn];
    s1 += __shfl_xor(s1, 16); s2 += __shfl_xor(s2, 16);
    s1 += __shfl_xor(s1, 32); s2 += __shfl_xor(s2, 32);
    if (lane < 16) {
      int oc = nn * 16 + lane;
      atomicAdd(&statsZ[oc], s1);
      atomicAdd(&statsZ[64 + oc], s2);
    }
  }
}

// ---------------- K4: finalize z BN scale/shift ----------------
__global__ __launch_bounds__(64) void k_zstat(const float* __restrict__ statsZ,
                                              const float* __restrict__ g_cls,
                                              const float* __restrict__ be_cls,
                                              const float* __restrict__ g_reg,
                                              const float* __restrict__ be_reg,
                                              float* __restrict__ zsc,
                                              float* __restrict__ zsh) {
  int t = threadIdx.x;  // 64
  float g = 1.f, be = 0.f;
  if (t < 36) { g = g_reg[t]; be = be_reg[t]; }
  else if (t < 54) { g = g_cls[t - 36]; be = be_cls[t - 36]; }
  float cnt = (float)MPIX;
  float m = statsZ[t] / cnt;
  float v = fmaxf(statsZ[64 + t] / cnt - m * m, 0.f);
  float s = g * rsqrtf(v + 1e-5f);
  zsc[t] = s;
  zsh[t] = be - m * s;
}

// ---------------- K5: BN-apply + softmax + anchor decode + outputs ----------------
__global__ __launch_bounds__(256) void k_dec(const unsigned short* __restrict__ zt,
                                             const float* __restrict__ zsc,
                                             const float* __restrict__ zsh,
                                             const int* __restrict__ imgsz,
                                             float* __restrict__ out) {
  int p = blockIdx.x * 256 + threadIdx.x;  // 131072
  float lim = (float)imgsz[0];
  float zn[64];
  {
    const uint4* zp4 = (const uint4*)(zt + (size_t)p * 64);
#pragma unroll
    for (int i = 0; i < 8; ++i) {
      uint4 v = zp4[i];
      unsigned a0 = v.x, a1 = v.y, a2 = v.z, a3 = v.w;
      zn[i * 8 + 0] = bf2f((unsigned short)(a0 & 0xffff));
      zn[i * 8 + 1] = bf2f((unsigned short)(a0 >> 16));
      zn[i * 8 + 2] = bf2f((unsigned short)(a1 & 0xffff));
      zn[i * 8 + 3] = bf2f((unsigned short)(a1 >> 16));
      zn[i * 8 + 4] = bf2f((unsigned short)(a2 & 0xffff));
      zn[i * 8 + 5] = bf2f((unsigned short)(a2 >> 16));
      zn[i * 8 + 6] = bf2f((unsigned short)(a3 & 0xffff));
      zn[i * 8 + 7] = bf2f((unsigned short)(a3 >> 16));
    }
#pragma unroll
    for (int i = 0; i < 54; ++i) zn[i] = zn[i] * zsc[i] + zsh[i];
  }
  int rem = p & 16383, h = rem >> 7, w = rem & 127;
  float fx = 16.f * (float)w, fy = 16.f * (float)h;
  size_t kbase = (size_t)p * 9;
  float* fgout = out;
  float* tsout = out + FGCNT;
  float* roout = out + FGCNT + TSCNT;
#pragma unroll
  for (int a = 0; a < 9; ++a) {
    float x1 = 20.f - 0.5f * AW[a] + fx;
    float y1 = 20.f - 0.5f * AH[a] + fy;
    float x2 = 19.f + 0.5f * AW[a] + fx;
    float y2 = 19.f + 0.5f * AH[a] + fy;
    float cx1 = fminf(fmaxf(x1 + zn[4 * a + 0], 0.f), lim);
    float cy1 = fminf(fmaxf(y1 + zn[4 * a + 1], 0.f), lim);
    float cx2 = fminf(fmaxf(x2 + zn[4 * a + 2], 0.f), lim);
    float cy2 = fminf(fmaxf(y2 + zn[4 * a + 3], 0.f), lim);
    float bw = cx2 - cx1, bh = cy2 - cy1;
    float cx = cx1 + 0.5f * bw, cy = cy1 + 0.5f * bh;
    float aw = AW[a] - 1.f, ah = AH[a] - 1.f;
    float acx = 19.5f + fx, acy = 19.5f + fy;
    float tx = (cx - acx) / aw, ty = (cy - acy) / ah;
    float tw = logf(fmaxf(bw / aw, 1e-30f));
    float th = logf(fmaxf(bh / ah, 1e-30f));
    float s0 = zn[36 + 2 * a], s1 = zn[36 + 2 * a + 1];
    float fg = 1.f / (1.f + expf(s0 - s1));
    fgout[kbase + a] = fg;
    size_t o4 = (kbase + a) * 4;
    tsout[o4 + 0] = tx; tsout[o4 + 1] = ty; tsout[o4 + 2] = tw; tsout[o4 + 3] = th;
    roout[o4 + 0] = cx; roout[o4 + 1] = cy; roout[o4 + 2] = bw; roout[o4 + 3] = bh;
  }
}

// ---------------- launch ----------------
extern "C" void kernel_launch(void* const* d_in, const int* in_sizes, int n_in,
                              void* d_out, int out_size, void* d_ws, size_t ws_size,
                              hipStream_t stream) {
  const float* x   = (const float*)d_in[0];
  const float* Wb  = (const float*)d_in[1];
  const float* bb  = (const float*)d_in[2];
  const float* gb  = (const float*)d_in[3];
  const float* beb = (const float*)d_in[4];
  const float* Wc  = (const float*)d_in[5];
  const float* bc  = (const float*)d_in[6];
  const float* gc  = (const float*)d_in[7];
  const float* bec = (const float*)d_in[8];
  const float* Wr  = (const float*)d_in[9];
  const float* br  = (const float*)d_in[10];
  const float* gr  = (const float*)d_in[11];
  const float* ber = (const float*)d_in[12];
  const int* imgsz = (const int*)d_in[13];

  char* ws = (char*)d_ws;
  const size_t OFF_XTP = 0;                        // 64*130*130*32*2 = 69,222,400
  const size_t OFF_Y   = 69222400;                 // 8*131072*32*2   = 67,108,864
  const size_t OFF_Z   = 136331264;                // 131072*64*2     = 16,777,216
  const size_t OFF_WT  = 153108480;                // 72*256*32*2     =  1,179,648
  const size_t OFF_W2  = 154288128;                // 8*64*32*2       =     32,768
  const size_t OFF_S   = 154320896;                // small area
  unsigned short* xt2  = (unsigned short*)(ws + OFF_XTP);
  unsigned short* yt2  = (unsigned short*)(ws + OFF_Y);
  unsigned short* zt   = (unsigned short*)(ws + OFF_Z);
  unsigned short* Wt2  = (unsigned short*)(ws + OFF_WT);
  unsigned short* W2t2 = (unsigned short*)(ws + OFF_W2);
  float* b2     = (float*)(ws + OFF_S);            // 64 f
  float* statsA = (float*)(ws + OFF_S + 256);      // 512 f
  float* statsZ = (float*)(ws + OFF_S + 2304);     // 128 f
  float* zsc    = (float*)(ws + OFF_S + 2816);     // 64 f
  float* zsh    = (float*)(ws + OFF_S + 3072);     // 64 f
  float* out = (float*)d_out;

  hipMemsetAsync(statsA, 0, (512 + 128) * sizeof(float), stream);
  k_wt  <<<2304, 256, 0, stream>>>(Wb, Wt2);
  k_tr  <<<8192, 256, 0, stream>>>(x, xt2);
  k_bord<<<516, 256, 0, stream>>>(xt2);
  k_conv<<<2048, 256, 0, stream>>>(xt2, Wt2, bb, yt2, statsA);
  k_fold<<<1, 256, 0, stream>>>(statsA, gb, beb, Wc, bc, Wr, br, W2t2, b2);
  k_mm2 <<<1024, 256, 0, stream>>>(yt2, W2t2, b2, zt, statsZ);
  k_zstat<<<1, 64, 0, stream>>>(statsZ, gc, bec, gr, ber, zsc, zsh);
  k_dec <<<512, 256, 0, stream>>>(zt, zsc, zsh, imgsz, out);
}

// Round 9
// 536.081 us; speedup vs baseline: 1.3973x; 1.0194x over previous
//
#include <hip/hip_runtime.h>
#include <stdint.h>

// ---------------- types / helpers ----------------
typedef short bf16x8 __attribute__((ext_vector_type(8)));
typedef float f32x4 __attribute__((ext_vector_type(4)));

#define AS1 __attribute__((address_space(1)))
#define AS3 __attribute__((address_space(3)))

static __device__ __forceinline__ void gl16(const void* g, void* l) {
  __builtin_amdgcn_global_load_lds((const AS1 void*)g, (AS3 void*)l, 16, 0, 0);
}

static __device__ __forceinline__ unsigned short f2bf(float f) {
  unsigned u = __float_as_uint(f);
  u = u + 0x7fffu + ((u >> 16) & 1u);
  return (unsigned short)(u >> 16);
}
static __device__ __forceinline__ float bf2f(unsigned short h) {
  return __uint_as_float(((unsigned)h) << 16);
}
static __device__ __forceinline__ float mishf(float x) {
  float sp = fmaxf(x, 0.f) + log1pf(expf(-fabsf(x)));
  float e2 = expf(-2.f * sp);
  float th = (1.f - e2) / (1.f + e2);
  return x * th;
}

// geometry
#define NIMG 8
#define HH 128
#define WW 128
#define HP 130
#define CIN 256
#define MPIX (NIMG * HH * WW)       // 131072
#define KTOT 2304                   // 72 steps of 32
#define FGCNT (MPIX * 9)            // 1179648
#define TSCNT (MPIX * 9 * 4)        // 4718592

__device__ __constant__ float AW[9] = {456.f, 912.f, 1824.f, 320.f, 640.f, 1280.f, 224.f, 448.f, 896.f};
__device__ __constant__ float AH[9] = {224.f, 448.f, 896.f, 320.f, 640.f, 1280.f, 448.f, 896.f, 1792.f};

// ---------------- K0a: conv weights -> Wt2[s][oc][32] bf16, s = kh*24+kw*8+icb ----------------
__global__ __launch_bounds__(256) void k_wt(const float* __restrict__ Wb,
                                            unsigned short* __restrict__ Wt2) {
  int d = blockIdx.x * 256 + threadIdx.x;  // 589824 = 72*256*32
  int c = d & 31, oc = (d >> 5) & 255, s = d >> 13;
  int kh = s / 24, r = s % 24, kw = r >> 3, icb = r & 7;
  int ic = icb * 32 + c;
  Wt2[d] = f2bf(Wb[((oc * 256 + ic) * 3 + kh) * 3 + kw]);
}

// ---------------- K0b: x (NCHW f32) -> xt2 (channel-blocked padded) interior ----------------
// xt2 layout: [icb(8)*8+n][130][130][32] bf16
__global__ __launch_bounds__(256) void k_tr(const float* __restrict__ x,
                                            unsigned short* __restrict__ xt2) {
  __shared__ float tile[32][129];
  int b = blockIdx.x;  // 8 n * 128 h * 8 icb = 8192
  int icb = b & 7, h = (b >> 3) & 127, n = b >> 10;
  int t = threadIdx.x;
  const float* src = x + (((size_t)(n * 256 + icb * 32) * 128 + h) * 128);
#pragma unroll
  for (int i = 0; i < 4; ++i) {
    int idx = t + 256 * i;          // 1024 float4 units
    int w4 = idx & 31, ic = idx >> 5;
    float4 v = *(const float4*)(src + (size_t)ic * 16384 + w4 * 4);
    tile[ic][w4 * 4 + 0] = v.x; tile[ic][w4 * 4 + 1] = v.y;
    tile[ic][w4 * 4 + 2] = v.z; tile[ic][w4 * 4 + 3] = v.w;
  }
  __syncthreads();
#pragma unroll
  for (int i = 0; i < 8; ++i) {
    int idx = t + 256 * i;          // 2048 bf16-pairs
    int icp = idx & 15, w = idx >> 4;
    unsigned lo = f2bf(tile[icp * 2][w]);
    unsigned hi = f2bf(tile[icp * 2 + 1][w]);
    size_t pix = ((size_t)(icb * 8 + n) * HP + (h + 1)) * HP + (w + 1);
    *(unsigned*)(xt2 + pix * 32 + icp * 2) = lo | (hi << 16);
  }
}

// ---------------- K0c: zero padded borders of xt2 ----------------
__global__ __launch_bounds__(256) void k_bord(unsigned short* __restrict__ xt2) {
  int tid = blockIdx.x * 256 + threadIdx.x;  // 64 planes * 516 border pix * 4 chunks = 132096
  int chunk = tid & 3, pix = tid >> 2;
  int nn = pix / 516, bp = pix % 516;        // nn = icb*8+n plane
  int hp, wp;
  if (bp < 130) { hp = 0; wp = bp; }
  else if (bp < 260) { hp = 129; wp = bp - 130; }
  else { int r = bp - 260; hp = 1 + (r >> 1); wp = (r & 1) ? 129 : 0; }
  size_t off = (((size_t)nn * HP + hp) * HP + wp) * 32 + chunk * 8;
  uint4 z = {0u, 0u, 0u, 0u};
  *(uint4*)(xt2 + off) = z;
}

// ---------------- K1: conv3x3 implicit GEMM — m97 structure + 2-phase dbuf ----------------
// M=131072, N=256, K=2304. BM=128 x BN=128, 4 waves, wave tile 64x64, acc[4][4].
// LDS region-major (0-conflict, R8): byte = region*1024 + q*256 + (idx&15)*16;
// gl16 dest linear, source contiguous 1KB per wave region.
// R9: catalog T3 "minimum 2-phase" with COMPILER barriers (R6/R7 = m141 lesson:
// no asm waitcnt / sched_barrier). Double buffer 2x16KB; STAGE(s+1 -> buf^1)
// issued right after the barrier, BEFORE frag reads + MFMA of step s -> its
// vmcnt(0) drain happens at the NEXT barrier with ~350cyc of compute in flight.
// (R8 = stage-then-barrier = zero hiding = 380us, MfmaUtil 17.9%.)
// Safety: top barrier orders all waves' step-(s-1) LDS reads before STAGE(s+1)
// can overwrite buf^1 (==buf of s-1), and drains STAGE(s) writes.
__global__ __launch_bounds__(256) void k_conv(const unsigned short* __restrict__ xt2,
                                              const unsigned short* __restrict__ Wt2,
                                              const float* __restrict__ b_base,
                                              unsigned short* __restrict__ yt2,
                                              float* __restrict__ statsA) {
  __shared__ __align__(16) char lds[32768];    // 2 x (A 8KB | B 8KB)
  int t = threadIdx.x;
  int lane = t & 63, w4 = t >> 6;              // 4 waves
  int wr = w4 >> 1, wc = w4 & 1;               // 2M x 2N wave grid, wave tile 64x64
  int row16 = lane & 15, kgl = lane >> 4;
  int pr = lane & 15, pq = lane >> 4;          // staging lane decomposition

  int bid = blockIdx.x;                        // 2048, %8==0 -> bijective
  int swz = (bid & 7) * 256 + (bid >> 3);      // XCD k owns contiguous 256 tiles
  int pixb = swz >> 1, oh = swz & 1;
  int n = pixb >> 7, h0 = pixb & 127;
  size_t M0 = (size_t)pixb * 128;

  f32x4 acc[4][4];
#pragma unroll
  for (int m = 0; m < 4; ++m)
#pragma unroll
    for (int nf = 0; nf < 4; ++nf) { f32x4 z = {0.f, 0.f, 0.f, 0.f}; acc[m][nf] = z; }

  // A: wave w4 stages regions 2w4, 2w4+1 (pixels 32w4 .. +31)
  const unsigned short* aS0 =
      xt2 + ((size_t)(n * HP + h0) * HP + w4 * 32 + pr) * 32 + pq * 8;
  const unsigned short* aS1 = aS0 + 16 * 32;
  // B: wave w4 stages regions 2w4, 2w4+1 (ocs oh*128 + 32w4 .. +31)
  const unsigned short* bS0 = Wt2 + (size_t)(oh * 128 + w4 * 32 + pr) * 32 + pq * 8;
  const unsigned short* bS1 = bS0 + 16 * 32;

  const size_t planeStride = (size_t)8 * HP * HP * 32;
  int aoffA = wr * 4096 + kgl * 256 + row16 * 16;   // + m*1024
  int aoffB = wc * 4096 + kgl * 256 + row16 * 16;   // + nf*1024

  auto STAGE = [&](int sv, int c_) {
    int icb_ = sv & 7;
    int khw = sv >> 3;                 // kh*3 + kw, 0..8 (s = kh*24 + kw*8 + icb)
    int kh_ = khw / 3;
    int kw_ = khw - kh_ * 3;
    size_t offA = (size_t)icb_ * planeStride + ((size_t)kh_ * HP + kw_) * 32;
    size_t offB = (size_t)sv * 8192;   // 256 oc * 32 shorts per k-step
    char* buf = lds + c_ * 16384;
    gl16(aS0 + offA, buf + (2 * w4) * 1024);
    gl16(aS1 + offA, buf + (2 * w4 + 1) * 1024);
    gl16(bS0 + offB, buf + 8192 + (2 * w4) * 1024);
    gl16(bS1 + offB, buf + 8192 + (2 * w4 + 1) * 1024);
  };

  STAGE(0, 0);
  int cur = 0;
  for (int s = 0; s < 72; ++s) {
    __syncthreads();                   // drains STAGE(s); orders reads vs overwrite
    if (s < 71) STAGE(s + 1, cur ^ 1); // issue early -> hidden under reads+MFMA
    const char* ab = lds + cur * 16384;
    const char* bb = ab + 8192;
    bf16x8 af[4], bfr[4];
#pragma unroll
    for (int m = 0; m < 4; ++m) af[m] = *(const bf16x8*)(ab + aoffA + m * 1024);
#pragma unroll
    for (int nf = 0; nf < 4; ++nf) bfr[nf] = *(const bf16x8*)(bb + aoffB + nf * 1024);
#pragma unroll
    for (int m = 0; m < 4; ++m)
#pragma unroll
      for (int nf = 0; nf < 4; ++nf)
        acc[m][nf] = __builtin_amdgcn_mfma_f32_16x16x32_bf16(af[m], bfr[nf], acc[m][nf], 0, 0, 0);
    cur ^= 1;
  }

  // epilogue: bias + mish, store channel-blocked yt2[oc>>5][pix][oc&31], stats
  float sums[4] = {0.f, 0.f, 0.f, 0.f}, sumq[4] = {0.f, 0.f, 0.f, 0.f};
#pragma unroll
  for (int nf = 0; nf < 4; ++nf) {
    int oc = oh * 128 + wc * 64 + nf * 16 + row16;
    float bias = b_base[oc];
    size_t obase = (size_t)(oc >> 5) * MPIX * 32 + (oc & 31);
#pragma unroll
    for (int m = 0; m < 4; ++m) {
#pragma unroll
      for (int j = 0; j < 4; ++j) {
        int p = wr * 64 + m * 16 + kgl * 4 + j;
        float y = mishf(acc[m][nf][j] + bias);
        yt2[obase + (M0 + p) * 32] = f2bf(y);
        sums[nf] += y; sumq[nf] += y * y;
      }
    }
  }
#pragma unroll
  for (int nf = 0; nf < 4; ++nf) {
    float s1 = sums[nf], s2 = sumq[nf];
    s1 += __shfl_xor(s1, 16); s2 += __shfl_xor(s2, 16);
    s1 += __shfl_xor(s1, 32); s2 += __shfl_xor(s2, 32);
    if (lane < 16) {
      int oc = oh * 128 + wc * 64 + nf * 16 + lane;
      atomicAdd(&statsA[oc], s1);
      atomicAdd(&statsA[256 + oc], s2);
    }
  }
}

// ---------------- K2: finalize base BN, fold into fused 1x1 weights ----------------
// W2t2 layout: [s(8)][64 oc][32] bf16
__global__ __launch_bounds__(256) void k_fold(const float* __restrict__ statsA,
                                              const float* __restrict__ g_base,
                                              const float* __restrict__ be_base,
                                              const float* __restrict__ W_cls,
                                              const float* __restrict__ b_cls,
                                              const float* __restrict__ W_reg,
                                              const float* __restrict__ b_reg,
                                              unsigned short* __restrict__ W2t2,
                                              float* __restrict__ b2) {
  __shared__ float sS[256], sT[256];
  int t = threadIdx.x;
  {
    float cnt = (float)MPIX;
    float m = statsA[t] / cnt;
    float v = fmaxf(statsA[256 + t] / cnt - m * m, 0.f);
    float s = g_base[t] * rsqrtf(v + 1e-5f);
    sS[t] = s;
    sT[t] = be_base[t] - m * s;
  }
  __syncthreads();
  if (t < 64) {
    float bias = 0.f;
    if (t < 36) bias = b_reg[t];
    else if (t < 54) bias = b_cls[t - 36];
    float acc = 0.f;
    for (int ic = 0; ic < 256; ++ic) {
      float w = 0.f;
      if (t < 36) w = W_reg[t * 256 + ic];
      else if (t < 54) w = W_cls[(t - 36) * 256 + ic];
      acc += w * sT[ic];
      W2t2[((size_t)(ic >> 5) * 64 + t) * 32 + (ic & 31)] = f2bf(w * sS[ic]);
    }
    b2[t] = bias + acc;
  }
}

// ---------------- K3: fused 1x1 heads GEMM (M=131072, N=64, K=256) + z stats ----------------
// Region-major LDS + 2-phase dbuf (same schedule as k_conv). 4 waves, 24KB LDS.
__global__ __launch_bounds__(256) void k_mm2(const unsigned short* __restrict__ yt2,
                                             const unsigned short* __restrict__ W2t2,
                                             const float* __restrict__ b2,
                                             unsigned short* __restrict__ zt,
                                             float* __restrict__ statsZ) {
  __shared__ __align__(16) char lds2[24576];   // 2 x (A 8KB | B 4KB)
  int t = threadIdx.x, lane = t & 63, w4 = t >> 6;   // 4 waves
  int row16 = lane & 15, kgl = lane >> 4;
  int pr = lane & 15, pq = lane >> 4;
  size_t pixbase = (size_t)blockIdx.x * 128;

  f32x4 acc[2][4];
#pragma unroll
  for (int m = 0; m < 2; ++m)
#pragma unroll
    for (int nn = 0; nn < 4; ++nn) { f32x4 z = {0.f, 0.f, 0.f, 0.f}; acc[m][nn] = z; }

  // A: wave w4 stages regions 2w4, 2w4+1 (pixels 32w4 .. +31)
  const unsigned short* aS0 = yt2 + (pixbase + w4 * 32 + pr) * 32 + pq * 8;
  const unsigned short* aS1 = aS0 + 16 * 32;
  // B: wave w4 stages region w4 (ocs 16w4 .. +15)
  const unsigned short* bS = W2t2 + (size_t)(w4 * 16 + pr) * 32 + pq * 8;

  int aoffA = w4 * 2048 + kgl * 256 + row16 * 16;  // + m*1024
  int aoffB = kgl * 256 + row16 * 16;              // + nn*1024

  auto STG = [&](int s, int c_) {
    size_t ao = (size_t)s * MPIX * 32;
    size_t bo = (size_t)s * 2048;          // 64 oc * 32
    char* buf = lds2 + c_ * 12288;
    gl16(aS0 + ao, buf + (2 * w4) * 1024);
    gl16(aS1 + ao, buf + (2 * w4 + 1) * 1024);
    gl16(bS + bo, buf + 8192 + w4 * 1024);
  };

  STG(0, 0);
  int cur = 0;
  for (int s = 0; s < 8; ++s) {
    __syncthreads();
    if (s < 7) STG(s + 1, cur ^ 1);
    const char* ab = lds2 + cur * 12288;
    const char* bb = ab + 8192;
    bf16x8 af[2], bfr[4];
#pragma unroll
    for (int m = 0; m < 2; ++m) af[m] = *(const bf16x8*)(ab + aoffA + m * 1024);
#pragma unroll
    for (int nn = 0; nn < 4; ++nn) bfr[nn] = *(const bf16x8*)(bb + aoffB + nn * 1024);
#pragma unroll
    for (int m = 0; m < 2; ++m)
#pragma unroll
      for (int nn = 0; nn < 4; ++nn)
        acc[m][nn] = __builtin_amdgcn_mfma_f32_16x16x32_bf16(af[m], bfr[nn], acc[m][nn], 0, 0, 0);
    cur ^= 1;
  }

  float sums[4] = {0.f, 0.f, 0.f, 0.f}, sumq[4] = {0.f, 0.f, 0.f, 0.f};
#pragma unroll
  for (int nn = 0; nn < 4; ++nn) {
    int oc = nn * 16 + row16;
    float bias = b2[oc];
#pragma unroll
    for (int m = 0; m < 2; ++m) {
#pragma unroll
      for (int j = 0; j < 4; ++j) {
        int p = w4 * 32 + m * 16 + kgl * 4 + j;
        float v = acc[m][nn][j] + bias;
        zt[(pixbase + p) * 64 + oc] = f2bf(v);
        sums[nn] += v; sumq[nn] += v * v;
      }
    }
  }
#pragma unroll
  for (int nn = 0; nn < 4; ++nn) {
    float s1 = sums[nn], s2 = sumq[nn];
    s1 += __shfl_xor(s1, 16); s2 += __shfl_xor(s2, 16);
    s1 += __shfl_xor(s1, 32); s2 += __shfl_xor(s2, 32);
    if (lane < 16) {
      int oc = nn * 16 + lane;
      atomicAdd(&statsZ[oc], s1);
      atomicAdd(&statsZ[64 + oc], s2);
    }
  }
}

// ---------------- K4: finalize z BN scale/shift ----------------
__global__ __launch_bounds__(64) void k_zstat(const float* __restrict__ statsZ,
                                              const float* __restrict__ g_cls,
                                              const float* __restrict__ be_cls,
                                              const float* __restrict__ g_reg,
                                              const float* __restrict__ be_reg,
                                              float* __restrict__ zsc,
                                              float* __restrict__ zsh) {
  int t = threadIdx.x;  // 64
  float g = 1.f, be = 0.f;
  if (t < 36) { g = g_reg[t]; be = be_reg[t]; }
  else if (t < 54) { g = g_cls[t - 36]; be = be_cls[t - 36]; }
  float cnt = (float)MPIX;
  float m = statsZ[t] / cnt;
  float v = fmaxf(statsZ[64 + t] / cnt - m * m, 0.f);
  float s = g * rsqrtf(v + 1e-5f);
  zsc[t] = s;
  zsh[t] = be - m * s;
}

// ---------------- K5: BN-apply + softmax + anchor decode + outputs ----------------
__global__ __launch_bounds__(256) void k_dec(const unsigned short* __restrict__ zt,
                                             const float* __restrict__ zsc,
                                             const float* __restrict__ zsh,
                                             const int* __restrict__ imgsz,
                                             float* __restrict__ out) {
  int p = blockIdx.x * 256 + threadIdx.x;  // 131072
  float lim = (float)imgsz[0];
  float zn[64];
  {
    const uint4* zp4 = (const uint4*)(zt + (size_t)p * 64);
#pragma unroll
    for (int i = 0; i < 8; ++i) {
      uint4 v = zp4[i];
      unsigned a0 = v.x, a1 = v.y, a2 = v.z, a3 = v.w;
      zn[i * 8 + 0] = bf2f((unsigned short)(a0 & 0xffff));
      zn[i * 8 + 1] = bf2f((unsigned short)(a0 >> 16));
      zn[i * 8 + 2] = bf2f((unsigned short)(a1 & 0xffff));
      zn[i * 8 + 3] = bf2f((unsigned short)(a1 >> 16));
      zn[i * 8 + 4] = bf2f((unsigned short)(a2 & 0xffff));
      zn[i * 8 + 5] = bf2f((unsigned short)(a2 >> 16));
      zn[i * 8 + 6] = bf2f((unsigned short)(a3 & 0xffff));
      zn[i * 8 + 7] = bf2f((unsigned short)(a3 >> 16));
    }
#pragma unroll
    for (int i = 0; i < 54; ++i) zn[i] = zn[i] * zsc[i] + zsh[i];
  }
  int rem = p & 16383, h = rem >> 7, w = rem & 127;
  float fx = 16.f * (float)w, fy = 16.f * (float)h;
  size_t kbase = (size_t)p * 9;
  float* fgout = out;
  float* tsout = out + FGCNT;
  float* roout = out + FGCNT + TSCNT;
#pragma unroll
  for (int a = 0; a < 9; ++a) {
    float x1 = 20.f - 0.5f * AW[a] + fx;
    float y1 = 20.f - 0.5f * AH[a] + fy;
    float x2 = 19.f + 0.5f * AW[a] + fx;
    float y2 = 19.f + 0.5f * AH[a] + fy;
    float cx1 = fminf(fmaxf(x1 + zn[4 * a + 0], 0.f), lim);
    float cy1 = fminf(fmaxf(y1 + zn[4 * a + 1], 0.f), lim);
    float cx2 = fminf(fmaxf(x2 + zn[4 * a + 2], 0.f), lim);
    float cy2 = fminf(fmaxf(y2 + zn[4 * a + 3], 0.f), lim);
    float bw = cx2 - cx1, bh = cy2 - cy1;
    float cx = cx1 + 0.5f * bw, cy = cy1 + 0.5f * bh;
    float aw = AW[a] - 1.f, ah = AH[a] - 1.f;
    float acx = 19.5f + fx, acy = 19.5f + fy;
    float tx = (cx - acx) / aw, ty = (cy - acy) / ah;
    float tw = logf(fmaxf(bw / aw, 1e-30f));
    float th = logf(fmaxf(bh / ah, 1e-30f));
    float s0 = zn[36 + 2 * a], s1 = zn[36 + 2 * a + 1];
    float fg = 1.f / (1.f + expf(s0 - s1));
    fgout[kbase + a] = fg;
    size_t o4 = (kbase + a) * 4;
    tsout[o4 + 0] = tx; tsout[o4 + 1] = ty; tsout[o4 + 2] = tw; tsout[o4 + 3] = th;
    roout[o4 + 0] = cx; roout[o4 + 1] = cy; roout[o4 + 2] = bw; roout[o4 + 3] = bh;
  }
}

// ---------------- launch ----------------
extern "C" void kernel_launch(void* const* d_in, const int* in_sizes, int n_in,
                              void* d_out, int out_size, void* d_ws, size_t ws_size,
                              hipStream_t stream) {
  const float* x   = (const float*)d_in[0];
  const float* Wb  = (const float*)d_in[1];
  const float* bb  = (const float*)d_in[2];
  const float* gb  = (const float*)d_in[3];
  const float* beb = (const float*)d_in[4];
  const float* Wc  = (const float*)d_in[5];
  const float* bc  = (const float*)d_in[6];
  const float* gc  = (const float*)d_in[7];
  const float* bec = (const float*)d_in[8];
  const float* Wr  = (const float*)d_in[9];
  const float* br  = (const float*)d_in[10];
  const float* gr  = (const float*)d_in[11];
  const float* ber = (const float*)d_in[12];
  const int* imgsz = (const int*)d_in[13];

  char* ws = (char*)d_ws;
  const size_t OFF_XTP = 0;                        // 64*130*130*32*2 = 69,222,400
  const size_t OFF_Y   = 69222400;                 // 8*131072*32*2   = 67,108,864
  const size_t OFF_Z   = 136331264;                // 131072*64*2     = 16,777,216
  const size_t OFF_WT  = 153108480;                // 72*256*32*2     =  1,179,648
  const size_t OFF_W2  = 154288128;                // 8*64*32*2       =     32,768
  const size_t OFF_S   = 154320896;                // small area
  unsigned short* xt2  = (unsigned short*)(ws + OFF_XTP);
  unsigned short* yt2  = (unsigned short*)(ws + OFF_Y);
  unsigned short* zt   = (unsigned short*)(ws + OFF_Z);
  unsigned short* Wt2  = (unsigned short*)(ws + OFF_WT);
  unsigned short* W2t2 = (unsigned short*)(ws + OFF_W2);
  float* b2     = (float*)(ws + OFF_S);            // 64 f
  float* statsA = (float*)(ws + OFF_S + 256);      // 512 f
  float* statsZ = (float*)(ws + OFF_S + 2304);     // 128 f
  float* zsc    = (float*)(ws + OFF_S + 2816);     // 64 f
  float* zsh    = (float*)(ws + OFF_S + 3072);     // 64 f
  float* out = (float*)d_out;

  hipMemsetAsync(statsA, 0, (512 + 128) * sizeof(float), stream);
  k_wt  <<<2304, 256, 0, stream>>>(Wb, Wt2);
  k_tr  <<<8192, 256, 0, stream>>>(x, xt2);
  k_bord<<<516, 256, 0, stream>>>(xt2);
  k_conv<<<2048, 256, 0, stream>>>(xt2, Wt2, bb, yt2, statsA);
  k_fold<<<1, 256, 0, stream>>>(statsA, gb, beb, Wc, bc, Wr, br, W2t2, b2);
  k_mm2 <<<1024, 256, 0, stream>>>(yt2, W2t2, b2, zt, statsZ);
  k_zstat<<<1, 64, 0, stream>>>(statsZ, gc, bec, gr, ber, zsc, zsh);
  k_dec <<<512, 256, 0, stream>>>(zt, zsc, zsh, imgsz, out);
}

// Round 10
// 532.390 us; speedup vs baseline: 1.4070x; 1.0069x over previous
//
#include <hip/hip_runtime.h>
#include <stdint.h>

// ---------------- types / helpers ----------------
typedef short bf16x8 __attribute__((ext_vector_type(8)));
typedef float f32x4 __attribute__((ext_vector_type(4)));

#define AS1 __attribute__((address_space(1)))
#define AS3 __attribute__((address_space(3)))

static __device__ __forceinline__ void gl16(const void* g, void* l) {
  __builtin_amdgcn_global_load_lds((const AS1 void*)g, (AS3 void*)l, 16, 0, 0);
}

static __device__ __forceinline__ unsigned short f2bf(float f) {
  unsigned u = __float_as_uint(f);
  u = u + 0x7fffu + ((u >> 16) & 1u);
  return (unsigned short)(u >> 16);
}
static __device__ __forceinline__ float bf2f(unsigned short h) {
  return __uint_as_float(((unsigned)h) << 16);
}
static __device__ __forceinline__ float mishf(float x) {
  float sp = fmaxf(x, 0.f) + log1pf(expf(-fabsf(x)));
  float e2 = expf(-2.f * sp);
  float th = (1.f - e2) / (1.f + e2);
  return x * th;
}

// geometry
#define NIMG 8
#define HH 128
#define WW 128
#define HP 130
#define CIN 256
#define MPIX (NIMG * HH * WW)       // 131072
#define KTOT 2304                   // 72 steps of 32
#define FGCNT (MPIX * 9)            // 1179648
#define TSCNT (MPIX * 9 * 4)        // 4718592

__device__ __constant__ float AW[9] = {456.f, 912.f, 1824.f, 320.f, 640.f, 1280.f, 224.f, 448.f, 896.f};
__device__ __constant__ float AH[9] = {224.f, 448.f, 896.f, 320.f, 640.f, 1280.f, 448.f, 896.f, 1792.f};

// ---------------- K0a: conv weights -> Wt2[s][oc][32] bf16, s = icb*9 + kh*3 + kw ----------------
// (icb-major K order: 9 consecutive steps reuse the same 3 input rows of one
//  plane -> A staging hits L1/L2; per-XCD working set ~1.1MB A + 1.15MB B fits L2.)
__global__ __launch_bounds__(256) void k_wt(const float* __restrict__ Wb,
                                            unsigned short* __restrict__ Wt2) {
  int d = blockIdx.x * 256 + threadIdx.x;  // 589824 = 72*256*32
  int c = d & 31, oc = (d >> 5) & 255, s = d >> 13;
  int icb = s / 9, khw = s % 9, kh = khw / 3, kw = khw % 3;
  int ic = icb * 32 + c;
  Wt2[d] = f2bf(Wb[((oc * 256 + ic) * 3 + kh) * 3 + kw]);
}

// ---------------- K0b: x (NCHW f32) -> xt2 (channel-blocked padded) interior ----------------
// xt2 layout: [icb(8)*8+n][130][130][32] bf16
__global__ __launch_bounds__(256) void k_tr(const float* __restrict__ x,
                                            unsigned short* __restrict__ xt2) {
  __shared__ float tile[32][129];
  int b = blockIdx.x;  // 8 n * 128 h * 8 icb = 8192
  int icb = b & 7, h = (b >> 3) & 127, n = b >> 10;
  int t = threadIdx.x;
  const float* src = x + (((size_t)(n * 256 + icb * 32) * 128 + h) * 128);
#pragma unroll
  for (int i = 0; i < 4; ++i) {
    int idx = t + 256 * i;          // 1024 float4 units
    int w4 = idx & 31, ic = idx >> 5;
    float4 v = *(const float4*)(src + (size_t)ic * 16384 + w4 * 4);
    tile[ic][w4 * 4 + 0] = v.x; tile[ic][w4 * 4 + 1] = v.y;
    tile[ic][w4 * 4 + 2] = v.z; tile[ic][w4 * 4 + 3] = v.w;
  }
  __syncthreads();
#pragma unroll
  for (int i = 0; i < 8; ++i) {
    int idx = t + 256 * i;          // 2048 bf16-pairs
    int icp = idx & 15, w = idx >> 4;
    unsigned lo = f2bf(tile[icp * 2][w]);
    unsigned hi = f2bf(tile[icp * 2 + 1][w]);
    size_t pix = ((size_t)(icb * 8 + n) * HP + (h + 1)) * HP + (w + 1);
    *(unsigned*)(xt2 + pix * 32 + icp * 2) = lo | (hi << 16);
  }
}

// ---------------- K0c: zero padded borders of xt2 ----------------
__global__ __launch_bounds__(256) void k_bord(unsigned short* __restrict__ xt2) {
  int tid = blockIdx.x * 256 + threadIdx.x;  // 64 planes * 516 border pix * 4 chunks = 132096
  int chunk = tid & 3, pix = tid >> 2;
  int nn = pix / 516, bp = pix % 516;        // nn = icb*8+n plane
  int hp, wp;
  if (bp < 130) { hp = 0; wp = bp; }
  else if (bp < 260) { hp = 129; wp = bp - 130; }
  else { int r = bp - 260; hp = 1 + (r >> 1); wp = (r & 1) ? 129 : 0; }
  size_t off = (((size_t)nn * HP + hp) * HP + wp) * 32 + chunk * 8;
  uint4 z = {0u, 0u, 0u, 0u};
  *(uint4*)(xt2 + off) = z;
}

// ---------------- K1: conv3x3 implicit GEMM — counted-vmcnt depth-2 pipeline ----------------
// M=131072, N=256, K=2304 (72 steps of 32, icb-major). BM=128 x BN=128, 4 waves,
// wave tile 64x64, acc[4][4]. LDS region-major (0-conflict, R8): byte =
// region*1024 + q*256 + (idx&15)*16; gl16 dest linear, source contiguous 1KB.
// R9 lesson: __syncthreads implies vmcnt(0) -> depth-1 dbuf gains nothing.
// R10: raw s_barrier + COUNTED vmcnt(4) (T4: never drain to 0 in the loop).
// 3 buffers x 16KB, depth 2. Safety: vmcnt(4) at step s ensures each wave's
// STAGE(s) (4 gl16) is complete before its barrier (only STAGE(s+1)'s 4 remain
// in flight); barrier s+1 orders all step-s LDS reads before STAGE(s+3)
// overwrites buf (s%3). All control flow wave-uniform.
__global__ __launch_bounds__(256) void k_conv(const unsigned short* __restrict__ xt2,
                                              const unsigned short* __restrict__ Wt2,
                                              const float* __restrict__ b_base,
                                              unsigned short* __restrict__ yt2,
                                              float* __restrict__ statsA) {
  __shared__ __align__(16) char lds[49152];    // 3 x (A 8KB | B 8KB)
  int t = threadIdx.x;
  int lane = t & 63, w4 = t >> 6;              // 4 waves
  int wr = w4 >> 1, wc = w4 & 1;               // 2M x 2N wave grid, wave tile 64x64
  int row16 = lane & 15, kgl = lane >> 4;
  int pr = lane & 15, pq = lane >> 4;          // staging lane decomposition

  int bid = blockIdx.x;                        // 2048, %8==0 -> bijective
  int swz = (bid & 7) * 256 + (bid >> 3);      // XCD k owns contiguous 256 tiles
  int pixb = swz >> 1, oh = swz & 1;
  int n = pixb >> 7, h0 = pixb & 127;
  size_t M0 = (size_t)pixb * 128;

  f32x4 acc[4][4];
#pragma unroll
  for (int m = 0; m < 4; ++m)
#pragma unroll
    for (int nf = 0; nf < 4; ++nf) { f32x4 z = {0.f, 0.f, 0.f, 0.f}; acc[m][nf] = z; }

  // A: wave w4 stages regions 2w4, 2w4+1 (pixels 32w4 .. +31)
  const unsigned short* aS0 =
      xt2 + ((size_t)(n * HP + h0) * HP + w4 * 32 + pr) * 32 + pq * 8;
  const unsigned short* aS1 = aS0 + 16 * 32;
  // B: wave w4 stages regions 2w4, 2w4+1 (ocs oh*128 + 32w4 .. +31)
  const unsigned short* bS0 = Wt2 + (size_t)(oh * 128 + w4 * 32 + pr) * 32 + pq * 8;
  const unsigned short* bS1 = bS0 + 16 * 32;

  const size_t planeStride = (size_t)8 * HP * HP * 32;
  int aoffA = wr * 4096 + kgl * 256 + row16 * 16;   // + m*1024
  int aoffB = wc * 4096 + kgl * 256 + row16 * 16;   // + nf*1024

  auto STAGE = [&](int sv, int b_) {
    // s = icb*9 + kh*3 + kw  (icb-major). Magic-div, all SALU-uniform:
    int icb_ = (sv * 57) >> 9;         // sv/9 for sv<512
    int khw = sv - icb_ * 9;
    int kh_ = (khw * 11) >> 5;         // khw/3 for khw<9
    int kw_ = khw - kh_ * 3;
    size_t offA = (size_t)icb_ * planeStride + ((size_t)kh_ * HP + kw_) * 32;
    size_t offB = (size_t)sv * 8192;   // 256 oc * 32 shorts per k-step
    char* buf = lds + b_ * 16384;
    gl16(aS0 + offA, buf + (2 * w4) * 1024);
    gl16(aS1 + offA, buf + (2 * w4 + 1) * 1024);
    gl16(bS0 + offB, buf + 8192 + (2 * w4) * 1024);
    gl16(bS1 + offB, buf + 8192 + (2 * w4 + 1) * 1024);
  };

  STAGE(0, 0);
  STAGE(1, 1);
  int cur = 0, nxt = 2;
  for (int s = 0; s < 72; ++s) {
    if (s < 71) { asm volatile("s_waitcnt vmcnt(4)" ::: "memory"); }
    else        { asm volatile("s_waitcnt vmcnt(0)" ::: "memory"); }
    __builtin_amdgcn_s_barrier();
    if (s < 70) STAGE(s + 2, nxt);
    const char* ab = lds + cur * 16384;
    const char* bb = ab + 8192;
    bf16x8 af[4], bfr[4];
#pragma unroll
    for (int m = 0; m < 4; ++m) af[m] = *(const bf16x8*)(ab + aoffA + m * 1024);
#pragma unroll
    for (int nf = 0; nf < 4; ++nf) bfr[nf] = *(const bf16x8*)(bb + aoffB + nf * 1024);
#pragma unroll
    for (int m = 0; m < 4; ++m)
#pragma unroll
      for (int nf = 0; nf < 4; ++nf)
        acc[m][nf] = __builtin_amdgcn_mfma_f32_16x16x32_bf16(af[m], bfr[nf], acc[m][nf], 0, 0, 0);
    cur = (cur == 2) ? 0 : cur + 1;
    nxt = (nxt == 2) ? 0 : nxt + 1;
  }

  // epilogue: bias + mish, store channel-blocked yt2[oc>>5][pix][oc&31], stats
  float sums[4] = {0.f, 0.f, 0.f, 0.f}, sumq[4] = {0.f, 0.f, 0.f, 0.f};
#pragma unroll
  for (int nf = 0; nf < 4; ++nf) {
    int oc = oh * 128 + wc * 64 + nf * 16 + row16;
    float bias = b_base[oc];
    size_t obase = (size_t)(oc >> 5) * MPIX * 32 + (oc & 31);
#pragma unroll
    for (int m = 0; m < 4; ++m) {
#pragma unroll
      for (int j = 0; j < 4; ++j) {
        int p = wr * 64 + m * 16 + kgl * 4 + j;
        float y = mishf(acc[m][nf][j] + bias);
        yt2[obase + (M0 + p) * 32] = f2bf(y);
        sums[nf] += y; sumq[nf] += y * y;
      }
    }
  }
#pragma unroll
  for (int nf = 0; nf < 4; ++nf) {
    float s1 = sums[nf], s2 = sumq[nf];
    s1 += __shfl_xor(s1, 16); s2 += __shfl_xor(s2, 16);
    s1 += __shfl_xor(s1, 32); s2 += __shfl_xor(s2, 32);
    if (lane < 16) {
      int oc = oh * 128 + wc * 64 + nf * 16 + lane;
      atomicAdd(&statsA[oc], s1);
      atomicAdd(&statsA[256 + oc], s2);
    }
  }
}

// ---------------- K2: finalize base BN, fold into fused 1x1 weights ----------------
// W2t2 layout: [s(8)][64 oc][32] bf16
__global__ __launch_bounds__(256) void k_fold(const float* __restrict__ statsA,
                                              const float* __restrict__ g_base,
                                              const float* __restrict__ be_base,
                                              const float* __restrict__ W_cls,
                                              const float* __restrict__ b_cls,
                                              const float* __restrict__ W_reg,
                                              const float* __restrict__ b_reg,
                                              unsigned short* __restrict__ W2t2,
                                              float* __restrict__ b2) {
  __shared__ float sS[256], sT[256];
  int t = threadIdx.x;
  {
    float cnt = (float)MPIX;
    float m = statsA[t] / cnt;
    float v = fmaxf(statsA[256 + t] / cnt - m * m, 0.f);
    float s = g_base[t] * rsqrtf(v + 1e-5f);
    sS[t] = s;
    sT[t] = be_base[t] - m * s;
  }
  __syncthreads();
  if (t < 64) {
    float bias = 0.f;
    if (t < 36) bias = b_reg[t];
    else if (t < 54) bias = b_cls[t - 36];
    float acc = 0.f;
    for (int ic = 0; ic < 256; ++ic) {
      float w = 0.f;
      if (t < 36) w = W_reg[t * 256 + ic];
      else if (t < 54) w = W_cls[(t - 36) * 256 + ic];
      acc += w * sT[ic];
      W2t2[((size_t)(ic >> 5) * 64 + t) * 32 + (ic & 31)] = f2bf(w * sS[ic]);
    }
    b2[t] = bias + acc;
  }
}

// ---------------- K3: fused 1x1 heads GEMM (M=131072, N=64, K=256) + z stats ----------------
// Region-major LDS + 2-phase dbuf. 4 waves, 24KB LDS.
__global__ __launch_bounds__(256) void k_mm2(const unsigned short* __restrict__ yt2,
                                             const unsigned short* __restrict__ W2t2,
                                             const float* __restrict__ b2,
                                             unsigned short* __restrict__ zt,
                                             float* __restrict__ statsZ) {
  __shared__ __align__(16) char lds2[24576];   // 2 x (A 8KB | B 4KB)
  int t = threadIdx.x, lane = t & 63, w4 = t >> 6;   // 4 waves
  int row16 = lane & 15, kgl = lane >> 4;
  int pr = lane & 15, pq = lane >> 4;
  size_t pixbase = (size_t)blockIdx.x * 128;

  f32x4 acc[2][4];
#pragma unroll
  for (int m = 0; m < 2; ++m)
#pragma unroll
    for (int nn = 0; nn < 4; ++nn) { f32x4 z = {0.f, 0.f, 0.f, 0.f}; acc[m][nn] = z; }

  // A: wave w4 stages regions 2w4, 2w4+1 (pixels 32w4 .. +31)
  const unsigned short* aS0 = yt2 + (pixbase + w4 * 32 + pr) * 32 + pq * 8;
  const unsigned short* aS1 = aS0 + 16 * 32;
  // B: wave w4 stages region w4 (ocs 16w4 .. +15)
  const unsigned short* bS = W2t2 + (size_t)(w4 * 16 + pr) * 32 + pq * 8;

  int aoffA = w4 * 2048 + kgl * 256 + row16 * 16;  // + m*1024
  int aoffB = kgl * 256 + row16 * 16;              // + nn*1024

  auto STG = [&](int s, int c_) {
    size_t ao = (size_t)s * MPIX * 32;
    size_t bo = (size_t)s * 2048;          // 64 oc * 32
    char* buf = lds2 + c_ * 12288;
    gl16(aS0 + ao, buf + (2 * w4) * 1024);
    gl16(aS1 + ao, buf + (2 * w4 + 1) * 1024);
    gl16(bS + bo, buf + 8192 + w4 * 1024);
  };

  STG(0, 0);
  int cur = 0;
  for (int s = 0; s < 8; ++s) {
    __syncthreads();
    if (s < 7) STG(s + 1, cur ^ 1);
    const char* ab = lds2 + cur * 12288;
    const char* bb = ab + 8192;
    bf16x8 af[2], bfr[4];
#pragma unroll
    for (int m = 0; m < 2; ++m) af[m] = *(const bf16x8*)(ab + aoffA + m * 1024);
#pragma unroll
    for (int nn = 0; nn < 4; ++nn) bfr[nn] = *(const bf16x8*)(bb + aoffB + nn * 1024);
#pragma unroll
    for (int m = 0; m < 2; ++m)
#pragma unroll
      for (int nn = 0; nn < 4; ++nn)
        acc[m][nn] = __builtin_amdgcn_mfma_f32_16x16x32_bf16(af[m], bfr[nn], acc[m][nn], 0, 0, 0);
    cur ^= 1;
  }

  float sums[4] = {0.f, 0.f, 0.f, 0.f}, sumq[4] = {0.f, 0.f, 0.f, 0.f};
#pragma unroll
  for (int nn = 0; nn < 4; ++nn) {
    int oc = nn * 16 + row16;
    float bias = b2[oc];
#pragma unroll
    for (int m = 0; m < 2; ++m) {
#pragma unroll
      for (int j = 0; j < 4; ++j) {
        int p = w4 * 32 + m * 16 + kgl * 4 + j;
        float v = acc[m][nn][j] + bias;
        zt[(pixbase + p) * 64 + oc] = f2bf(v);
        sums[nn] += v; sumq[nn] += v * v;
      }
    }
  }
#pragma unroll
  for (int nn = 0; nn < 4; ++nn) {
    float s1 = sums[nn], s2 = sumq[nn];
    s1 += __shfl_xor(s1, 16); s2 += __shfl_xor(s2, 16);
    s1 += __shfl_xor(s1, 32); s2 += __shfl_xor(s2, 32);
    if (lane < 16) {
      int oc = nn * 16 + lane;
      atomicAdd(&statsZ[oc], s1);
      atomicAdd(&statsZ[64 + oc], s2);
    }
  }
}

// ---------------- K4: finalize z BN scale/shift ----------------
__global__ __launch_bounds__(64) void k_zstat(const float* __restrict__ statsZ,
                                              const float* __restrict__ g_cls,
                                              const float* __restrict__ be_cls,
                                              const float* __restrict__ g_reg,
                                              const float* __restrict__ be_reg,
                                              float* __restrict__ zsc,
                                              float* __restrict__ zsh) {
  int t = threadIdx.x;  // 64
  float g = 1.f, be = 0.f;
  if (t < 36) { g = g_reg[t]; be = be_reg[t]; }
  else if (t < 54) { g = g_cls[t - 36]; be = be_cls[t - 36]; }
  float cnt = (float)MPIX;
  float m = statsZ[t] / cnt;
  float v = fmaxf(statsZ[64 + t] / cnt - m * m, 0.f);
  float s = g * rsqrtf(v + 1e-5f);
  zsc[t] = s;
  zsh[t] = be - m * s;
}

// ---------------- K5: BN-apply + softmax + anchor decode + outputs ----------------
__global__ __launch_bounds__(256) void k_dec(const unsigned short* __restrict__ zt,
                                             const float* __restrict__ zsc,
                                             const float* __restrict__ zsh,
                                             const int* __restrict__ imgsz,
                                             float* __restrict__ out) {
  int p = blockIdx.x * 256 + threadIdx.x;  // 131072
  float lim = (float)imgsz[0];
  float zn[64];
  {
    const uint4* zp4 = (const uint4*)(zt + (size_t)p * 64);
#pragma unroll
    for (int i = 0; i < 8; ++i) {
      uint4 v = zp4[i];
      unsigned a0 = v.x, a1 = v.y, a2 = v.z, a3 = v.w;
      zn[i * 8 + 0] = bf2f((unsigned short)(a0 & 0xffff));
      zn[i * 8 + 1] = bf2f((unsigned short)(a0 >> 16));
      zn[i * 8 + 2] = bf2f((unsigned short)(a1 & 0xffff));
      zn[i * 8 + 3] = bf2f((unsigned short)(a1 >> 16));
      zn[i * 8 + 4] = bf2f((unsigned short)(a2 & 0xffff));
      zn[i * 8 + 5] = bf2f((unsigned short)(a2 >> 16));
      zn[i * 8 + 6] = bf2f((unsigned short)(a3 & 0xffff));
      zn[i * 8 + 7] = bf2f((unsigned short)(a3 >> 16));
    }
#pragma unroll
    for (int i = 0; i < 54; ++i) zn[i] = zn[i] * zsc[i] + zsh[i];
  }
  int rem = p & 16383, h = rem >> 7, w = rem & 127;
  float fx = 16.f * (float)w, fy = 16.f * (float)h;
  size_t kbase = (size_t)p * 9;
  float* fgout = out;
  float* tsout = out + FGCNT;
  float* roout = out + FGCNT + TSCNT;
#pragma unroll
  for (int a = 0; a < 9; ++a) {
    float x1 = 20.f - 0.5f * AW[a] + fx;
    float y1 = 20.f - 0.5f * AH[a] + fy;
    float x2 = 19.f + 0.5f * AW[a] + fx;
    float y2 = 19.f + 0.5f * AH[a] + fy;
    float cx1 = fminf(fmaxf(x1 + zn[4 * a + 0], 0.f), lim);
    float cy1 = fminf(fmaxf(y1 + zn[4 * a + 1], 0.f), lim);
    float cx2 = fminf(fmaxf(x2 + zn[4 * a + 2], 0.f), lim);
    float cy2 = fminf(fmaxf(y2 + zn[4 * a + 3], 0.f), lim);
    float bw = cx2 - cx1, bh = cy2 - cy1;
    float cx = cx1 + 0.5f * bw, cy = cy1 + 0.5f * bh;
    float aw = AW[a] - 1.f, ah = AH[a] - 1.f;
    float acx = 19.5f + fx, acy = 19.5f + fy;
    float tx = (cx - acx) / aw, ty = (cy - acy) / ah;
    float tw = logf(fmaxf(bw / aw, 1e-30f));
    float th = logf(fmaxf(bh / ah, 1e-30f));
    float s0 = zn[36 + 2 * a], s1 = zn[36 + 2 * a + 1];
    float fg = 1.f / (1.f + expf(s0 - s1));
    fgout[kbase + a] = fg;
    size_t o4 = (kbase + a) * 4;
    tsout[o4 + 0] = tx; tsout[o4 + 1] = ty; tsout[o4 + 2] = tw; tsout[o4 + 3] = th;
    roout[o4 + 0] = cx; roout[o4 + 1] = cy; roout[o4 + 2] = bw; roout[o4 + 3] = bh;
  }
}

// ---------------- launch ----------------
extern "C" void kernel_launch(void* const* d_in, const int* in_sizes, int n_in,
                              void* d_out, int out_size, void* d_ws, size_t ws_size,
                              hipStream_t stream) {
  const float* x   = (const float*)d_in[0];
  const float* Wb  = (const float*)d_in[1];
  const float* bb  = (const float*)d_in[2];
  const float* gb  = (const float*)d_in[3];
  const float* beb = (const float*)d_in[4];
  const float* Wc  = (const float*)d_in[5];
  const float* bc  = (const float*)d_in[6];
  const float* gc  = (const float*)d_in[7];
  const float* bec = (const float*)d_in[8];
  const float* Wr  = (const float*)d_in[9];
  const float* br  = (const float*)d_in[10];
  const float* gr  = (const float*)d_in[11];
  const float* ber = (const float*)d_in[12];
  const int* imgsz = (const int*)d_in[13];

  char* ws = (char*)d_ws;
  const size_t OFF_XTP = 0;                        // 64*130*130*32*2 = 69,222,400
  const size_t OFF_Y   = 69222400;                 // 8*131072*32*2   = 67,108,864
  const size_t OFF_Z   = 136331264;                // 131072*64*2     = 16,777,216
  const size_t OFF_WT  = 153108480;                // 72*256*32*2     =  1,179,648
  const size_t OFF_W2  = 154288128;                // 8*64*32*2       =     32,768
  const size_t OFF_S   = 154320896;                // small area
  unsigned short* xt2  = (unsigned short*)(ws + OFF_XTP);
  unsigned short* yt2  = (unsigned short*)(ws + OFF_Y);
  unsigned short* zt   = (unsigned short*)(ws + OFF_Z);
  unsigned short* Wt2  = (unsigned short*)(ws + OFF_WT);
  unsigned short* W2t2 = (unsigned short*)(ws + OFF_W2);
  float* b2     = (float*)(ws + OFF_S);            // 64 f
  float* statsA = (float*)(ws + OFF_S + 256);      // 512 f
  float* statsZ = (float*)(ws + OFF_S + 2304);     // 128 f
  float* zsc    = (float*)(ws + OFF_S + 2816);     // 64 f
  float* zsh    = (float*)(ws + OFF_S + 3072);     // 64 f
  float* out = (float*)d_out;

  hipMemsetAsync(statsA, 0, (512 + 128) * sizeof(float), stream);
  k_wt  <<<2304, 256, 0, stream>>>(Wb, Wt2);
  k_tr  <<<8192, 256, 0, stream>>>(x, xt2);
  k_bord<<<516, 256, 0, stream>>>(xt2);
  k_conv<<<2048, 256, 0, stream>>>(xt2, Wt2, bb, yt2, statsA);
  k_fold<<<1, 256, 0, stream>>>(statsA, gb, beb, Wc, bc, Wr, br, W2t2, b2);
  k_mm2 <<<1024, 256, 0, stream>>>(yt2, W2t2, b2, zt, statsZ);
  k_zstat<<<1, 64, 0, stream>>>(statsZ, gc, bec, gr, ber, zsc, zsh);
  k_dec <<<512, 256, 0, stream>>>(zt, zsc, zsh, imgsz, out);
}